// Round 4
// baseline (626.256 us; speedup 1.0000x reference)
//
#include <hip/hip_runtime.h>
#include <hip/hip_bf16.h>
#include <math.h>

#define NN 100000
#define NE 1600000
// IN = HID = 64, OUT = 40

typedef unsigned long long ull;

// ---------------------------------------------------------------------------
// 1) degree histogram
// ---------------------------------------------------------------------------
__global__ void deg_kernel(const int* __restrict__ dst, int* __restrict__ deg) {
    const int t = blockIdx.x * blockDim.x + threadIdx.x;
    if (t * 4 < NE) {
        const int4 d4 = ((const int4*)dst)[t];
        atomicAdd(&deg[d4.x], 1);
        atomicAdd(&deg[d4.y], 1);
        atomicAdd(&deg[d4.z], 1);
        atomicAdd(&deg[d4.w], 1);
    }
}

// ---------------------------------------------------------------------------
// 2) row allocation via wave-scan + global cursor
// ---------------------------------------------------------------------------
__global__ void alloc_kernel(const int* __restrict__ deg,
                             int* __restrict__ rowstart,
                             int* __restrict__ curpos,
                             int* __restrict__ cursor) {
    const int d    = blockIdx.x * blockDim.x + threadIdx.x;
    const int lane = threadIdx.x & 63;
    const int dg   = (d < NN) ? deg[d] : 0;
    int inc = dg;
    for (int off = 1; off < 64; off <<= 1) {
        int tv = __shfl_up(inc, off, 64);
        if (lane >= off) inc += tv;
    }
    const int wavesum = __shfl(inc, 63, 64);
    int base = 0;
    if (lane == 63) base = atomicAdd(cursor, wavesum);
    base = __shfl(base, 63, 64);
    if (d < NN) {
        const int start = base + inc - dg;
        rowstart[d] = start;
        curpos[d]   = start;
    }
}

// ---------------------------------------------------------------------------
// 3) bucket fill: rec[p] = (u_bits << 32) | src, grouped by dst
// ---------------------------------------------------------------------------
__global__ void bucket_kernel(const int* __restrict__ src,
                              const int* __restrict__ dst,
                              const float* __restrict__ u,
                              int* __restrict__ curpos,
                              ull* __restrict__ rec) {
    const int t = blockIdx.x * blockDim.x + threadIdx.x;
    if (t * 4 < NE) {
        const int4   s4 = ((const int4*)src)[t];
        const int4   d4 = ((const int4*)dst)[t];
        const float4 u4 = ((const float4*)u)[t];
        int p;
        p = atomicAdd(&curpos[d4.x], 1);
        rec[p] = ((ull)__float_as_uint(u4.x) << 32) | (unsigned)s4.x;
        p = atomicAdd(&curpos[d4.y], 1);
        rec[p] = ((ull)__float_as_uint(u4.y) << 32) | (unsigned)s4.y;
        p = atomicAdd(&curpos[d4.z], 1);
        rec[p] = ((ull)__float_as_uint(u4.z) << 32) | (unsigned)s4.z;
        p = atomicAdd(&curpos[d4.w], 1);
        rec[p] = ((ull)__float_as_uint(u4.w) << 32) | (unsigned)s4.w;
    }
}

// ---------------------------------------------------------------------------
// Fused layer 1. Block = 256 threads = 4 waves, 64-node tile.
//  - stage x-tile transposed bf16 into sXT (coalesced global reads)
//  - gather: each wave handles 4 nodes concurrently (16 lanes x float4 each),
//    no shuffles, no reduces; writes aggregates transposed bf16 into sAT
//  - GEMM: lane = node, wave w owns cols 16w..16w+15; A/x from LDS
//    (lane-consecutive, conflict-free), W via wave-uniform scalar loads
//  - h tile bounced through LDS, written coalesced
// ---------------------------------------------------------------------------
__global__ __launch_bounds__(256) void flayer1_kernel(
        const int* __restrict__ rowstart, const int* __restrict__ deg,
        const ull* __restrict__ rec, const float* __restrict__ x,
        const float* __restrict__ W1, const float* __restrict__ root1,
        const float* __restrict__ b1, float* __restrict__ h) {
    __shared__ __align__(16) __hip_bfloat16 sAT[128][68];  // 17408 B  (A^T)
    __shared__ __align__(16) __hip_bfloat16 sXT[64][68];   //  8704 B  (x^T)
    const int tid  = threadIdx.x;
    const int w    = tid >> 6;
    const int lane = tid & 63;
    const int base = blockIdx.x * 64;

    // ---- stage x^T tile (bf16) ----
    {
        const int r  = tid >> 4;    // 0..15
        const int c4 = tid & 15;
        #pragma unroll
        for (int p = 0; p < 4; ++p) {
            const int row  = p * 16 + r;
            const int node = base + row;
            float4 v = make_float4(0.f, 0.f, 0.f, 0.f);
            if (node < NN) v = ((const float4*)x)[(size_t)node * 16 + c4];
            sXT[c4 * 4 + 0][row] = __float2bfloat16(v.x);
            sXT[c4 * 4 + 1][row] = __float2bfloat16(v.y);
            sXT[c4 * 4 + 2][row] = __float2bfloat16(v.z);
            sXT[c4 * 4 + 3][row] = __float2bfloat16(v.w);
        }
    }

    // ---- gather: 4 passes x 4 concurrent nodes per wave ----
    {
        const int grp = lane >> 4;   // node slot within wave
        const int f   = lane & 15;   // float4 feature slot
        for (int pass = 0; pass < 4; ++pass) {
            const int nl   = w * 16 + pass * 4 + grp;
            const int node = base + nl;
            int dg = 0, st = 0;
            if (node < NN) { dg = deg[node]; st = rowstart[node]; }
            float4 sum = make_float4(0.f, 0.f, 0.f, 0.f);
            float4 smu = make_float4(0.f, 0.f, 0.f, 0.f);
            #pragma unroll 4
            for (int i = 0; i < dg; ++i) {
                const ull r    = rec[(size_t)(st + i)];
                const float u2 = __uint_as_float((unsigned)(r >> 32));
                const float4 v = ((const float4*)x)[(size_t)(unsigned)(r & 0xffffffffu) * 16 + f];
                sum.x += v.x; sum.y += v.y; sum.z += v.z; sum.w += v.w;
                smu.x = fmaf(u2, v.x, smu.x);
                smu.y = fmaf(u2, v.y, smu.y);
                smu.z = fmaf(u2, v.z, smu.z);
                smu.w = fmaf(u2, v.w, smu.w);
            }
            const float inv = 1.0f / fmaxf((float)dg, 1.0f);
            sAT[4 * f + 0][nl] = __float2bfloat16((sum.x - smu.x) * inv);
            sAT[4 * f + 1][nl] = __float2bfloat16((sum.y - smu.y) * inv);
            sAT[4 * f + 2][nl] = __float2bfloat16((sum.z - smu.z) * inv);
            sAT[4 * f + 3][nl] = __float2bfloat16((sum.w - smu.w) * inv);
            sAT[64 + 4 * f + 0][nl] = __float2bfloat16(smu.x * inv);
            sAT[64 + 4 * f + 1][nl] = __float2bfloat16(smu.y * inv);
            sAT[64 + 4 * f + 2][nl] = __float2bfloat16(smu.z * inv);
            sAT[64 + 4 * f + 3][nl] = __float2bfloat16(smu.w * inv);
        }
    }
    __syncthreads();

    // ---- GEMM: lane = node, 16 cols per wave ----
    const int cb = w * 16;
    float acc[16];
    #pragma unroll
    for (int c = 0; c < 16; ++c) acc[c] = 0.f;
    #pragma unroll 4
    for (int k = 0; k < 128; ++k) {
        const float a = __bfloat162float(sAT[k][lane]);
        const float* __restrict__ wr = W1 + k * 64 + cb;
        #pragma unroll
        for (int c = 0; c < 16; ++c) acc[c] = fmaf(a, wr[c], acc[c]);
    }
    #pragma unroll 4
    for (int k = 0; k < 64; ++k) {
        const float a = __bfloat162float(sXT[k][lane]);
        const float* __restrict__ wr = root1 + k * 64 + cb;
        #pragma unroll
        for (int c = 0; c < 16; ++c) acc[c] = fmaf(a, wr[c], acc[c]);
    }
    __syncthreads();   // all waves done reading sAT/sXT

    // ---- bounce h-tile (fp32, stride 68) + coalesced store ----
    float* bounce = (float*)&sAT[0][0];    // 64*68*4 = 17408 B, fits exactly
    #pragma unroll
    for (int c = 0; c < 16; ++c) {
        const float vv = acc[c] + b1[cb + c];
        bounce[lane * 68 + cb + c] = (vv > 0.f) ? vv : (__expf(vv) - 1.f);
    }
    __syncthreads();
    {
        const int tile_n = (NN - base < 64) ? (NN - base) : 64;
        float4* __restrict__ h4 = (float4*)h;
        for (int fi = tid; fi < tile_n * 16; fi += 256) {
            const int row = fi >> 4, c4 = fi & 15;
            h4[(size_t)base * 16 + fi] = *(const float4*)&bounce[row * 68 + c4 * 4];
        }
    }
}

// ---------------------------------------------------------------------------
// Fused layer 2 + log_softmax. Same structure; OUT=40, 10 cols/wave.
// ---------------------------------------------------------------------------
__global__ __launch_bounds__(256) void flayer2_kernel(
        const int* __restrict__ rowstart, const int* __restrict__ deg,
        const ull* __restrict__ rec, const float* __restrict__ hbuf,
        const float* __restrict__ W2, const float* __restrict__ root2,
        const float* __restrict__ b2, float* __restrict__ out) {
    __shared__ __align__(16) __hip_bfloat16 sAT[128][68];
    __shared__ __align__(16) __hip_bfloat16 sXT[64][68];
    __shared__ float sLse[64];
    const int tid  = threadIdx.x;
    const int w    = tid >> 6;
    const int lane = tid & 63;
    const int base = blockIdx.x * 64;

    // ---- stage h^T tile (bf16) ----
    {
        const int r  = tid >> 4;
        const int c4 = tid & 15;
        #pragma unroll
        for (int p = 0; p < 4; ++p) {
            const int row  = p * 16 + r;
            const int node = base + row;
            float4 v = make_float4(0.f, 0.f, 0.f, 0.f);
            if (node < NN) v = ((const float4*)hbuf)[(size_t)node * 16 + c4];
            sXT[c4 * 4 + 0][row] = __float2bfloat16(v.x);
            sXT[c4 * 4 + 1][row] = __float2bfloat16(v.y);
            sXT[c4 * 4 + 2][row] = __float2bfloat16(v.z);
            sXT[c4 * 4 + 3][row] = __float2bfloat16(v.w);
        }
    }

    // ---- gather ----
    {
        const int grp = lane >> 4;
        const int f   = lane & 15;
        for (int pass = 0; pass < 4; ++pass) {
            const int nl   = w * 16 + pass * 4 + grp;
            const int node = base + nl;
            int dg = 0, st = 0;
            if (node < NN) { dg = deg[node]; st = rowstart[node]; }
            float4 sum = make_float4(0.f, 0.f, 0.f, 0.f);
            float4 smu = make_float4(0.f, 0.f, 0.f, 0.f);
            #pragma unroll 4
            for (int i = 0; i < dg; ++i) {
                const ull r    = rec[(size_t)(st + i)];
                const float u2 = __uint_as_float((unsigned)(r >> 32));
                const float4 v = ((const float4*)hbuf)[(size_t)(unsigned)(r & 0xffffffffu) * 16 + f];
                sum.x += v.x; sum.y += v.y; sum.z += v.z; sum.w += v.w;
                smu.x = fmaf(u2, v.x, smu.x);
                smu.y = fmaf(u2, v.y, smu.y);
                smu.z = fmaf(u2, v.z, smu.z);
                smu.w = fmaf(u2, v.w, smu.w);
            }
            const float inv = 1.0f / fmaxf((float)dg, 1.0f);
            sAT[4 * f + 0][nl] = __float2bfloat16((sum.x - smu.x) * inv);
            sAT[4 * f + 1][nl] = __float2bfloat16((sum.y - smu.y) * inv);
            sAT[4 * f + 2][nl] = __float2bfloat16((sum.z - smu.z) * inv);
            sAT[4 * f + 3][nl] = __float2bfloat16((sum.w - smu.w) * inv);
            sAT[64 + 4 * f + 0][nl] = __float2bfloat16(smu.x * inv);
            sAT[64 + 4 * f + 1][nl] = __float2bfloat16(smu.y * inv);
            sAT[64 + 4 * f + 2][nl] = __float2bfloat16(smu.z * inv);
            sAT[64 + 4 * f + 3][nl] = __float2bfloat16(smu.w * inv);
        }
    }
    __syncthreads();

    // ---- GEMM: lane = node, 10 cols per wave ----
    const int cb = w * 10;
    float acc[10];
    #pragma unroll
    for (int c = 0; c < 10; ++c) acc[c] = 0.f;
    #pragma unroll 4
    for (int k = 0; k < 128; ++k) {
        const float a = __bfloat162float(sAT[k][lane]);
        const float* __restrict__ wr = W2 + k * 40 + cb;
        #pragma unroll
        for (int c = 0; c < 10; ++c) acc[c] = fmaf(a, wr[c], acc[c]);
    }
    #pragma unroll 4
    for (int k = 0; k < 64; ++k) {
        const float a = __bfloat162float(sXT[k][lane]);
        const float* __restrict__ wr = root2 + k * 40 + cb;
        #pragma unroll
        for (int c = 0; c < 10; ++c) acc[c] = fmaf(a, wr[c], acc[c]);
    }
    __syncthreads();   // done reading sAT/sXT

    // ---- logits into LDS (stride 44), per-node lse, coalesced store ----
    float* sOut = (float*)&sAT[0][0];      // 64*44*4 = 11264 B, fits
    #pragma unroll
    for (int c = 0; c < 10; ++c) sOut[lane * 44 + cb + c] = acc[c] + b2[cb + c];
    __syncthreads();
    if (tid < 64) {
        float mx = -3.0e38f;
        #pragma unroll
        for (int c = 0; c < 40; ++c) mx = fmaxf(mx, sOut[tid * 44 + c]);
        float s = 0.f;
        #pragma unroll
        for (int c = 0; c < 40; ++c) s += __expf(sOut[tid * 44 + c] - mx);
        sLse[tid] = mx + __logf(s);
    }
    __syncthreads();
    {
        const int tile_n = (NN - base < 64) ? (NN - base) : 64;
        float4* __restrict__ out4 = (float4*)out;
        for (int fi = tid; fi < tile_n * 10; fi += 256) {
            const int row = fi / 10, c4 = fi - row * 10;
            float4 v = *(const float4*)&sOut[row * 44 + c4 * 4];
            const float l = sLse[row];
            v.x -= l; v.y -= l; v.z -= l; v.w -= l;
            out4[(size_t)base * 10 + fi] = v;
        }
    }
}

// ---------------------------------------------------------------------------
extern "C" void kernel_launch(void* const* d_in, const int* in_sizes, int n_in,
                              void* d_out, int out_size, void* d_ws, size_t ws_size,
                              hipStream_t stream) {
    const float* x     = (const float*)d_in[0];
    const int*   ei    = (const int*)  d_in[1];
    const float* u     = (const float*)d_in[2];
    const float* W1    = (const float*)d_in[3];
    const float* root1 = (const float*)d_in[4];
    const float* b1    = (const float*)d_in[5];
    const float* W2    = (const float*)d_in[6];
    const float* root2 = (const float*)d_in[7];
    const float* b2    = (const float*)d_in[8];
    float*       out   = (float*)d_out;

    const int* src = ei;
    const int* dst = ei + NE;

    // ws layout: deg | curpos | cursor(+pad) | rowstart | rec(u64 E) | h
    char* p = (char*)d_ws;
    int* deg      = (int*)p;  p += (size_t)4 * NN;
    int* curpos   = (int*)p;  p += (size_t)4 * NN;
    int* cursor   = (int*)p;  p += 16;
    int* rowstart = (int*)p;  p += (size_t)4 * NN;
    ull* rec      = (ull*)p;  p += (size_t)8 * NE;
    float* h      = (float*)p;

    hipMemsetAsync(deg, 0, (size_t)(2 * 4 * NN + 16), stream);

    const int EB = (NE / 4 + 255) / 256;
    deg_kernel<<<EB, 256, 0, stream>>>(dst, deg);
    alloc_kernel<<<(NN + 255) / 256, 256, 0, stream>>>(deg, rowstart, curpos, cursor);
    bucket_kernel<<<EB, 256, 0, stream>>>(src, dst, u, curpos, rec);

    const int NB = (NN + 63) / 64;
    flayer1_kernel<<<NB, 256, 0, stream>>>(rowstart, deg, rec, x, W1, root1, b1, h);
    flayer2_kernel<<<NB, 256, 0, stream>>>(rowstart, deg, rec, h, W2, root2, b2, out);
}

// Round 6
// 457.013 us; speedup vs baseline: 1.3703x; 1.3703x over previous
//
#include <hip/hip_runtime.h>
#include <math.h>

#define NN 100000
#define NE 1600000
// IN = HID = 64, OUT = 40

typedef unsigned long long ull;

__device__ __forceinline__ unsigned short f2bf(float f) {
    unsigned b = __float_as_uint(f);
    return (unsigned short)((b + 0x7fffu + ((b >> 16) & 1u)) >> 16);
}

// ---------------------------------------------------------------------------
// 1) degree histogram
// ---------------------------------------------------------------------------
__global__ void deg_kernel(const int* __restrict__ dst, int* __restrict__ deg) {
    const int t = blockIdx.x * blockDim.x + threadIdx.x;
    if (t * 4 < NE) {
        const int4 d4 = ((const int4*)dst)[t];
        atomicAdd(&deg[d4.x], 1);
        atomicAdd(&deg[d4.y], 1);
        atomicAdd(&deg[d4.z], 1);
        atomicAdd(&deg[d4.w], 1);
    }
}

// ---------------------------------------------------------------------------
// 2) row allocation via wave-scan + global cursor
// ---------------------------------------------------------------------------
__global__ void alloc_kernel(const int* __restrict__ deg,
                             int* __restrict__ rowstart,
                             int* __restrict__ curpos,
                             int* __restrict__ cursor) {
    const int d    = blockIdx.x * blockDim.x + threadIdx.x;
    const int lane = threadIdx.x & 63;
    const int dg   = (d < NN) ? deg[d] : 0;
    int inc = dg;
    for (int off = 1; off < 64; off <<= 1) {
        int tv = __shfl_up(inc, off, 64);
        if (lane >= off) inc += tv;
    }
    const int wavesum = __shfl(inc, 63, 64);
    int base = 0;
    if (lane == 63) base = atomicAdd(cursor, wavesum);
    base = __shfl(base, 63, 64);
    if (d < NN) {
        const int start = base + inc - dg;
        rowstart[d] = start;
        curpos[d]   = start;
    }
}

// ---------------------------------------------------------------------------
// 3) bucket fill: rec[p] = (u_bits << 32) | src, grouped by dst
// ---------------------------------------------------------------------------
__global__ void bucket_kernel(const int* __restrict__ src,
                              const int* __restrict__ dst,
                              const float* __restrict__ u,
                              int* __restrict__ curpos,
                              ull* __restrict__ rec) {
    const int t = blockIdx.x * blockDim.x + threadIdx.x;
    if (t * 4 < NE) {
        const int4   s4 = ((const int4*)src)[t];
        const int4   d4 = ((const int4*)dst)[t];
        const float4 u4 = ((const float4*)u)[t];
        int p;
        p = atomicAdd(&curpos[d4.x], 1);
        rec[p] = ((ull)__float_as_uint(u4.x) << 32) | (unsigned)s4.x;
        p = atomicAdd(&curpos[d4.y], 1);
        rec[p] = ((ull)__float_as_uint(u4.y) << 32) | (unsigned)s4.y;
        p = atomicAdd(&curpos[d4.z], 1);
        rec[p] = ((ull)__float_as_uint(u4.z) << 32) | (unsigned)s4.z;
        p = atomicAdd(&curpos[d4.w], 1);
        rec[p] = ((ull)__float_as_uint(u4.w) << 32) | (unsigned)s4.w;
    }
}

// ---------------------------------------------------------------------------
// 4) aggregate: CSR gather, NO LDS, max occupancy. 16 threads per node,
//    thread owns a float4 feature slot; 8-deep unrolled edge loop gives 8
//    independent rec->gather chains in flight per lane.
//    Writes A[node][0:64]=(sum - sum_u)/deg, A[node][64:128]=sum_u/deg (bf16).
// ---------------------------------------------------------------------------
__global__ __launch_bounds__(256, 6) void agg_kernel(
        const int* __restrict__ rowstart, const int* __restrict__ deg,
        const ull* __restrict__ rec, const float* __restrict__ feat,
        unsigned short* __restrict__ A) {
    const int t    = blockIdx.x * 256 + threadIdx.x;
    const int node = t >> 4;
    const int f    = t & 15;
    if (node >= NN) return;
    const int dg = deg[node];
    const int st = rowstart[node];
    const float4* __restrict__ f4 = (const float4*)feat;

    float4 sum = make_float4(0.f, 0.f, 0.f, 0.f);
    float4 smu = make_float4(0.f, 0.f, 0.f, 0.f);
    int i = 0;
    for (; i + 8 <= dg; i += 8) {
        #pragma unroll
        for (int jj = 0; jj < 8; ++jj) {
            const ull r    = rec[(size_t)(st + i + jj)];
            const float u2 = __uint_as_float((unsigned)(r >> 32));
            const float4 v = f4[(size_t)(unsigned)(r & 0xffffffffu) * 16 + f];
            sum.x += v.x; sum.y += v.y; sum.z += v.z; sum.w += v.w;
            smu.x = fmaf(u2, v.x, smu.x);
            smu.y = fmaf(u2, v.y, smu.y);
            smu.z = fmaf(u2, v.z, smu.z);
            smu.w = fmaf(u2, v.w, smu.w);
        }
    }
    #pragma unroll 4
    for (; i < dg; ++i) {
        const ull r    = rec[(size_t)(st + i)];
        const float u2 = __uint_as_float((unsigned)(r >> 32));
        const float4 v = f4[(size_t)(unsigned)(r & 0xffffffffu) * 16 + f];
        sum.x += v.x; sum.y += v.y; sum.z += v.z; sum.w += v.w;
        smu.x = fmaf(u2, v.x, smu.x);
        smu.y = fmaf(u2, v.y, smu.y);
        smu.z = fmaf(u2, v.z, smu.z);
        smu.w = fmaf(u2, v.w, smu.w);
    }
    const float inv = 1.0f / fmaxf((float)dg, 1.0f);
    union { ushort4 q; unsigned short s[4]; } p0, p1;
    p0.s[0] = f2bf((sum.x - smu.x) * inv);
    p0.s[1] = f2bf((sum.y - smu.y) * inv);
    p0.s[2] = f2bf((sum.z - smu.z) * inv);
    p0.s[3] = f2bf((sum.w - smu.w) * inv);
    p1.s[0] = f2bf(smu.x * inv);
    p1.s[1] = f2bf(smu.y * inv);
    p1.s[2] = f2bf(smu.z * inv);
    p1.s[3] = f2bf(smu.w * inv);
    *(ushort4*)&A[(size_t)node * 128 + 4 * f]      = p0.q;
    *(ushort4*)&A[(size_t)node * 128 + 64 + 4 * f] = p1.q;
}

// ---------------------------------------------------------------------------
// 5) update layer 1: h = elu(A@[W1_0;W1_1] + x@root1 + b1). 64-node tile,
//    A^T (decoded bf16->fp32) and x^T staged in LDS (stride 67), lane = node,
//    wave w -> cols 16w..16w+15, W via wave-uniform scalar loads.
// ---------------------------------------------------------------------------
__global__ __launch_bounds__(256) void upd1_kernel(
        const unsigned short* __restrict__ A, const float* __restrict__ x,
        const float* __restrict__ W1, const float* __restrict__ root1,
        const float* __restrict__ b1, float* __restrict__ h) {
    __shared__ float sAT[128][67];
    __shared__ float sXT[64][67];
    const int tid  = threadIdx.x;
    const int w    = tid >> 6;
    const int lane = tid & 63;
    const int base = blockIdx.x * 64;

    // stage A^T: 16 col-slots x 8 bf16 (uint4) covers all 128 columns
    {
        const int c = tid & 15;   // column slot: bf16 cols c*8 .. c*8+7
        const int r = tid >> 4;   // 0..15
        #pragma unroll
        for (int p = 0; p < 4; ++p) {
            const int row  = p * 16 + r;
            const int node = base + row;
            uint4 raw = make_uint4(0u, 0u, 0u, 0u);
            if (node < NN) raw = *(const uint4*)&A[(size_t)node * 128 + c * 8];
            sAT[c * 8 + 0][row] = __uint_as_float(raw.x << 16);
            sAT[c * 8 + 1][row] = __uint_as_float(raw.x & 0xffff0000u);
            sAT[c * 8 + 2][row] = __uint_as_float(raw.y << 16);
            sAT[c * 8 + 3][row] = __uint_as_float(raw.y & 0xffff0000u);
            sAT[c * 8 + 4][row] = __uint_as_float(raw.z << 16);
            sAT[c * 8 + 5][row] = __uint_as_float(raw.z & 0xffff0000u);
            sAT[c * 8 + 6][row] = __uint_as_float(raw.w << 16);
            sAT[c * 8 + 7][row] = __uint_as_float(raw.w & 0xffff0000u);
        }
    }
    // stage x^T
    {
        const int c4 = tid & 15;
        const int r  = tid >> 4;
        #pragma unroll
        for (int p = 0; p < 4; ++p) {
            const int row  = p * 16 + r;
            const int node = base + row;
            float4 v = make_float4(0.f, 0.f, 0.f, 0.f);
            if (node < NN) v = ((const float4*)x)[(size_t)node * 16 + c4];
            sXT[c4 * 4 + 0][row] = v.x;
            sXT[c4 * 4 + 1][row] = v.y;
            sXT[c4 * 4 + 2][row] = v.z;
            sXT[c4 * 4 + 3][row] = v.w;
        }
    }
    __syncthreads();

    const int cb = __builtin_amdgcn_readfirstlane(w * 16);
    float acc[16];
    #pragma unroll
    for (int c = 0; c < 16; ++c) acc[c] = 0.f;
    #pragma unroll 4
    for (int k = 0; k < 128; ++k) {
        const float a = sAT[k][lane];
        const float* __restrict__ wr = W1 + k * 64 + cb;
        #pragma unroll
        for (int c = 0; c < 16; ++c) acc[c] = fmaf(a, wr[c], acc[c]);
    }
    #pragma unroll 4
    for (int k = 0; k < 64; ++k) {
        const float a = sXT[k][lane];
        const float* __restrict__ wr = root1 + k * 64 + cb;
        #pragma unroll
        for (int c = 0; c < 16; ++c) acc[c] = fmaf(a, wr[c], acc[c]);
    }
    __syncthreads();   // done reading sAT/sXT

    // bounce h-tile through LDS (stride 68), coalesced store
    float* bounce = (float*)&sAT[0][0];   // 64*68*4 B fits in sAT region
    #pragma unroll
    for (int c = 0; c < 16; ++c) {
        const float vv = acc[c] + b1[cb + c];
        bounce[lane * 68 + cb + c] = (vv > 0.f) ? vv : (__expf(vv) - 1.f);
    }
    __syncthreads();
    {
        const int tile_n = (NN - base < 64) ? (NN - base) : 64;
        float4* __restrict__ h4 = (float4*)h;
        for (int fi = tid; fi < tile_n * 16; fi += 256) {
            const int row = fi >> 4, c4 = fi & 15;
            h4[(size_t)base * 16 + fi] = *(const float4*)&bounce[row * 68 + c4 * 4];
        }
    }
}

// ---------------------------------------------------------------------------
// 6) update layer 2 + log_softmax. Same structure; 10 cols/wave.
// ---------------------------------------------------------------------------
__global__ __launch_bounds__(256) void upd2_kernel(
        const unsigned short* __restrict__ A, const float* __restrict__ hbuf,
        const float* __restrict__ W2, const float* __restrict__ root2,
        const float* __restrict__ b2, float* __restrict__ out) {
    __shared__ float sAT[128][67];
    __shared__ float sXT[64][67];
    __shared__ float sLse[64];
    const int tid  = threadIdx.x;
    const int w    = tid >> 6;
    const int lane = tid & 63;
    const int base = blockIdx.x * 64;

    {
        const int c = tid & 15;
        const int r = tid >> 4;
        #pragma unroll
        for (int p = 0; p < 4; ++p) {
            const int row  = p * 16 + r;
            const int node = base + row;
            uint4 raw = make_uint4(0u, 0u, 0u, 0u);
            if (node < NN) raw = *(const uint4*)&A[(size_t)node * 128 + c * 8];
            sAT[c * 8 + 0][row] = __uint_as_float(raw.x << 16);
            sAT[c * 8 + 1][row] = __uint_as_float(raw.x & 0xffff0000u);
            sAT[c * 8 + 2][row] = __uint_as_float(raw.y << 16);
            sAT[c * 8 + 3][row] = __uint_as_float(raw.y & 0xffff0000u);
            sAT[c * 8 + 4][row] = __uint_as_float(raw.z << 16);
            sAT[c * 8 + 5][row] = __uint_as_float(raw.z & 0xffff0000u);
            sAT[c * 8 + 6][row] = __uint_as_float(raw.w << 16);
            sAT[c * 8 + 7][row] = __uint_as_float(raw.w & 0xffff0000u);
        }
    }
    {
        const int c4 = tid & 15;
        const int r  = tid >> 4;
        #pragma unroll
        for (int p = 0; p < 4; ++p) {
            const int row  = p * 16 + r;
            const int node = base + row;
            float4 v = make_float4(0.f, 0.f, 0.f, 0.f);
            if (node < NN) v = ((const float4*)hbuf)[(size_t)node * 16 + c4];
            sXT[c4 * 4 + 0][row] = v.x;
            sXT[c4 * 4 + 1][row] = v.y;
            sXT[c4 * 4 + 2][row] = v.z;
            sXT[c4 * 4 + 3][row] = v.w;
        }
    }
    __syncthreads();

    const int cb = __builtin_amdgcn_readfirstlane(w * 10);
    float acc[10];
    #pragma unroll
    for (int c = 0; c < 10; ++c) acc[c] = 0.f;
    #pragma unroll 4
    for (int k = 0; k < 128; ++k) {
        const float a = sAT[k][lane];
        const float* __restrict__ wr = W2 + k * 40 + cb;
        #pragma unroll
        for (int c = 0; c < 10; ++c) acc[c] = fmaf(a, wr[c], acc[c]);
    }
    #pragma unroll 4
    for (int k = 0; k < 64; ++k) {
        const float a = sXT[k][lane];
        const float* __restrict__ wr = root2 + k * 40 + cb;
        #pragma unroll
        for (int c = 0; c < 10; ++c) acc[c] = fmaf(a, wr[c], acc[c]);
    }
    __syncthreads();

    float* sOut = (float*)&sAT[0][0];   // 64*44*4 B
    #pragma unroll
    for (int c = 0; c < 10; ++c) sOut[lane * 44 + cb + c] = acc[c] + b2[cb + c];
    __syncthreads();
    if (tid < 64) {
        float mx = -3.0e38f;
        #pragma unroll
        for (int c = 0; c < 40; ++c) mx = fmaxf(mx, sOut[tid * 44 + c]);
        float s = 0.f;
        #pragma unroll
        for (int c = 0; c < 40; ++c) s += __expf(sOut[tid * 44 + c] - mx);
        sLse[tid] = mx + __logf(s);
    }
    __syncthreads();
    {
        const int tile_n = (NN - base < 64) ? (NN - base) : 64;
        float4* __restrict__ out4 = (float4*)out;
        for (int fi = tid; fi < tile_n * 10; fi += 256) {
            const int row = fi / 10, c4 = fi - row * 10;
            float4 v = *(const float4*)&sOut[row * 44 + c4 * 4];
            const float l = sLse[row];
            v.x -= l; v.y -= l; v.z -= l; v.w -= l;
            out4[(size_t)base * 10 + fi] = v;
        }
    }
}

// ---------------------------------------------------------------------------
extern "C" void kernel_launch(void* const* d_in, const int* in_sizes, int n_in,
                              void* d_out, int out_size, void* d_ws, size_t ws_size,
                              hipStream_t stream) {
    const float* x     = (const float*)d_in[0];
    const int*   ei    = (const int*)  d_in[1];
    const float* u     = (const float*)d_in[2];
    const float* W1    = (const float*)d_in[3];
    const float* root1 = (const float*)d_in[4];
    const float* b1    = (const float*)d_in[5];
    const float* W2    = (const float*)d_in[6];
    const float* root2 = (const float*)d_in[7];
    const float* b2    = (const float*)d_in[8];
    float*       out   = (float*)d_out;

    const int* src = ei;
    const int* dst = ei + NE;

    // ws: deg | curpos | cursor(+pad) | rowstart | rec(u64 E) | A(bf16 N*128) | h
    char* p = (char*)d_ws;
    int* deg      = (int*)p;  p += (size_t)4 * NN;
    int* curpos   = (int*)p;  p += (size_t)4 * NN;
    int* cursor   = (int*)p;  p += 16;
    int* rowstart = (int*)p;  p += (size_t)4 * NN;
    ull* rec      = (ull*)p;  p += (size_t)8 * NE;
    unsigned short* A = (unsigned short*)p;  p += (size_t)2 * NN * 128;
    float* h      = (float*)p;

    hipMemsetAsync(deg, 0, (size_t)(2 * 4 * NN + 16), stream);

    const int EB = (NE / 4 + 255) / 256;
    deg_kernel<<<EB, 256, 0, stream>>>(dst, deg);
    alloc_kernel<<<(NN + 255) / 256, 256, 0, stream>>>(deg, rowstart, curpos, cursor);
    bucket_kernel<<<EB, 256, 0, stream>>>(src, dst, u, curpos, rec);

    const int AB = (NN * 16 + 255) / 256;   // 16 threads per node
    const int NB = (NN + 63) / 64;
    agg_kernel <<<AB, 256, 0, stream>>>(rowstart, deg, rec, x, A);
    upd1_kernel<<<NB, 256, 0, stream>>>(A, x, W1, root1, b1, h);
    agg_kernel <<<AB, 256, 0, stream>>>(rowstart, deg, rec, h, A);
    upd2_kernel<<<NB, 256, 0, stream>>>(A, h, W2, root2, b2, out);
}

// Round 7
// 402.947 us; speedup vs baseline: 1.5542x; 1.1342x over previous
//
#include <hip/hip_runtime.h>
#include <math.h>

#define NN 100000
#define NE 1600000
#define NBINS 391          // bin = dst >> 8 ; 100000/256 -> 0..390
// IN = HID = 64, OUT = 40

typedef unsigned long long ull;

__device__ __forceinline__ unsigned short f2bf(float f) {
    unsigned b = __float_as_uint(f);
    return (unsigned short)((b + 0x7fffu + ((b >> 16) & 1u)) >> 16);
}

// ---------------------------------------------------------------------------
// 1) degree histogram + bin histogram (LDS-staged)
// ---------------------------------------------------------------------------
__global__ __launch_bounds__(256) void deg_hist_kernel(
        const int* __restrict__ dst, int* __restrict__ deg,
        int* __restrict__ binCnt) {
    __shared__ int hist[512];
    const int t = threadIdx.x;
    hist[t] = 0; hist[t + 256] = 0;
    __syncthreads();
    const int b4 = blockIdx.x * 512;   // int4 base
    #pragma unroll
    for (int k = 0; k < 2; ++k) {
        const int i4 = b4 + k * 256 + t;
        if (i4 * 4 < NE) {
            const int4 d4 = ((const int4*)dst)[i4];
            atomicAdd(&deg[d4.x], 1); atomicAdd(&hist[d4.x >> 8], 1);
            atomicAdd(&deg[d4.y], 1); atomicAdd(&hist[d4.y >> 8], 1);
            atomicAdd(&deg[d4.z], 1); atomicAdd(&hist[d4.z >> 8], 1);
            atomicAdd(&deg[d4.w], 1); atomicAdd(&hist[d4.w >> 8], 1);
        }
    }
    __syncthreads();
    if (hist[t])       atomicAdd(&binCnt[t],       hist[t]);
    if (hist[t + 256]) atomicAdd(&binCnt[t + 256], hist[t + 256]);
}

// ---------------------------------------------------------------------------
// 2a) exclusive scan of binCnt[512] -> binStart[513]; binCur = binStart
// ---------------------------------------------------------------------------
__global__ __launch_bounds__(256) void scan_bins_kernel(
        const int* __restrict__ binCnt, int* __restrict__ binStart,
        int* __restrict__ binCur) {
    __shared__ int sa[512], sb[512];
    const int t = threadIdx.x;
    sa[t] = binCnt[t]; sa[t + 256] = binCnt[t + 256];
    __syncthreads();
    int* cur = sa; int* nxt = sb;
    for (int off = 1; off < 512; off <<= 1) {
        for (int j = t; j < 512; j += 256)
            nxt[j] = cur[j] + ((j >= off) ? cur[j - off] : 0);
        __syncthreads();
        int* tmp = cur; cur = nxt; nxt = tmp;
    }
    for (int j = t; j < 512; j += 256) {
        const int ex = (j == 0) ? 0 : cur[j - 1];
        binStart[j] = ex;
        binCur[j]   = ex;
    }
    if (t == 0) binStart[512] = cur[511];
}

// ---------------------------------------------------------------------------
// 2b) per-bin exclusive scan of deg -> rowstart (node-ordered CSR), curpos
// ---------------------------------------------------------------------------
__global__ __launch_bounds__(256) void scan_nodes_kernel(
        const int* __restrict__ deg, const int* __restrict__ binStart,
        int* __restrict__ rowstart, int* __restrict__ curpos) {
    __shared__ int wsum[4];
    const int b = blockIdx.x;
    const int t = threadIdx.x;
    const int n = b * 256 + t;
    const int d = (n < NN) ? deg[n] : 0;
    const int lane = t & 63, w = t >> 6;
    int inc = d;
    for (int off = 1; off < 64; off <<= 1) {
        int v = __shfl_up(inc, off, 64);
        if (lane >= off) inc += v;
    }
    if (lane == 63) wsum[w] = inc;
    __syncthreads();
    int add = 0;
    for (int i = 0; i < 4; ++i) if (i < w) add += wsum[i];
    const int excl = binStart[b] + add + inc - d;
    if (n < NN) { rowstart[n] = excl; curpos[n] = excl; }
}

// ---------------------------------------------------------------------------
// 3) binned scatter with LDS reorder: edges -> brec grouped by bin,
//    coalesced full-line global writes. brec = [uq:15|dst:17]<<32 | src.
// ---------------------------------------------------------------------------
__global__ __launch_bounds__(256) void p3_bin_scatter_kernel(
        const int* __restrict__ src, const int* __restrict__ dst,
        const float* __restrict__ u, int* __restrict__ binCur,
        ull* __restrict__ brec) {
    __shared__ int cnt[512], lstart[512], gbase[512], lcur[512];
    __shared__ int sa[512], sb[512];
    __shared__ ull buf[2048];
    const int t = threadIdx.x;
    cnt[t] = 0; cnt[t + 256] = 0;
    __syncthreads();
    const int base = blockIdx.x * 2048;
    int mysrc[8], mydst[8];
    float myu[8];
    #pragma unroll
    for (int k = 0; k < 8; ++k) {
        const int i = base + k * 256 + t;
        if (i < NE) {
            mydst[k] = dst[i]; mysrc[k] = src[i]; myu[k] = u[i];
            atomicAdd(&cnt[mydst[k] >> 8], 1);
        } else {
            mydst[k] = -1;
        }
    }
    __syncthreads();
    // scan cnt -> lstart (exclusive)
    sa[t] = cnt[t]; sa[t + 256] = cnt[t + 256];
    __syncthreads();
    int* cur = sa; int* nxt = sb;
    for (int off = 1; off < 512; off <<= 1) {
        for (int j = t; j < 512; j += 256)
            nxt[j] = cur[j] + ((j >= off) ? cur[j - off] : 0);
        __syncthreads();
        int* tmp = cur; cur = nxt; nxt = tmp;
    }
    for (int j = t; j < 512; j += 256) {
        const int ex = (j == 0) ? 0 : cur[j - 1];
        lstart[j] = ex;
        lcur[j]   = ex;
    }
    __syncthreads();
    // reserve global ranges (1 atomic per non-empty bin)
    for (int j = t; j < 512; j += 256) {
        const int c = cnt[j];
        gbase[j] = c ? atomicAdd(&binCur[j], c) : 0;
    }
    // scatter into LDS grouped by bin
    #pragma unroll
    for (int k = 0; k < 8; ++k) {
        if (mydst[k] >= 0) {
            const int b = mydst[k] >> 8;
            const int lp = atomicAdd(&lcur[b], 1);
            int uq = (int)(myu[k] * 32768.0f + 0.5f);
            if (uq > 32767) uq = 32767;
            const unsigned hi = ((unsigned)uq << 17) | (unsigned)mydst[k];
            buf[lp] = ((ull)hi << 32) | (unsigned)mysrc[k];
        }
    }
    __syncthreads();
    const int total = lstart[511] + cnt[511];
    for (int i = t; i < total; i += 256) {
        const ull r = buf[i];
        const int d = (int)((unsigned)(r >> 32) & 0x1FFFFu);
        const int b = d >> 8;
        brec[(size_t)(gbase[b] + (i - lstart[b]))] = r;
    }
}

// ---------------------------------------------------------------------------
// 4) per-bin final scatter: brec -> rec4 in CSR order. Writes confined to the
//    bin's contiguous window (L2-local). rec4 = [uq:15]<<17 | src.
// ---------------------------------------------------------------------------
__global__ __launch_bounds__(256) void p4_final_kernel(
        const ull* __restrict__ brec, const int* __restrict__ binStart,
        int* __restrict__ curpos, unsigned* __restrict__ rec4) {
    const int b = blockIdx.x;
    const int s = binStart[b], e = binStart[b + 1];
    for (int i = s + threadIdx.x; i < e; i += 256) {
        const ull r = brec[i];
        const unsigned hi = (unsigned)(r >> 32);
        const int d = hi & 0x1FFFFu;
        const int p = atomicAdd(&curpos[d], 1);
        rec4[p] = (hi & 0xFFFE0000u) | (unsigned)(r & 0x1FFFFu);
    }
}

// ---------------------------------------------------------------------------
// 5) aggregate: CSR gather, NO LDS, max occupancy. 16 threads per node,
//    thread owns a float4 feature slot; 8-deep unrolled edge loop.
//    Writes A[node][0:64]=(sum - sum_u)/deg, A[node][64:128]=sum_u/deg (bf16).
// ---------------------------------------------------------------------------
__global__ __launch_bounds__(256, 6) void agg_kernel(
        const int* __restrict__ rowstart, const int* __restrict__ deg,
        const unsigned* __restrict__ rec4, const float* __restrict__ feat,
        unsigned short* __restrict__ A) {
    const int t    = blockIdx.x * 256 + threadIdx.x;
    const int node = t >> 4;
    const int f    = t & 15;
    if (node >= NN) return;
    const int dg = deg[node];
    const int st = rowstart[node];
    const float4* __restrict__ f4 = (const float4*)feat;
    const float UQS = 1.0f / 32768.0f;

    float4 sum = make_float4(0.f, 0.f, 0.f, 0.f);
    float4 smu = make_float4(0.f, 0.f, 0.f, 0.f);
    int i = 0;
    for (; i + 8 <= dg; i += 8) {
        #pragma unroll
        for (int jj = 0; jj < 8; ++jj) {
            const unsigned r = rec4[(size_t)(st + i + jj)];
            const float u2 = (float)(r >> 17) * UQS;
            const float4 v = f4[(size_t)(r & 0x1FFFFu) * 16 + f];
            sum.x += v.x; sum.y += v.y; sum.z += v.z; sum.w += v.w;
            smu.x = fmaf(u2, v.x, smu.x);
            smu.y = fmaf(u2, v.y, smu.y);
            smu.z = fmaf(u2, v.z, smu.z);
            smu.w = fmaf(u2, v.w, smu.w);
        }
    }
    #pragma unroll 4
    for (; i < dg; ++i) {
        const unsigned r = rec4[(size_t)(st + i)];
        const float u2 = (float)(r >> 17) * UQS;
        const float4 v = f4[(size_t)(r & 0x1FFFFu) * 16 + f];
        sum.x += v.x; sum.y += v.y; sum.z += v.z; sum.w += v.w;
        smu.x = fmaf(u2, v.x, smu.x);
        smu.y = fmaf(u2, v.y, smu.y);
        smu.z = fmaf(u2, v.z, smu.z);
        smu.w = fmaf(u2, v.w, smu.w);
    }
    const float inv = 1.0f / fmaxf((float)dg, 1.0f);
    union { ushort4 q; unsigned short s[4]; } p0, p1;
    p0.s[0] = f2bf((sum.x - smu.x) * inv);
    p0.s[1] = f2bf((sum.y - smu.y) * inv);
    p0.s[2] = f2bf((sum.z - smu.z) * inv);
    p0.s[3] = f2bf((sum.w - smu.w) * inv);
    p1.s[0] = f2bf(smu.x * inv);
    p1.s[1] = f2bf(smu.y * inv);
    p1.s[2] = f2bf(smu.z * inv);
    p1.s[3] = f2bf(smu.w * inv);
    *(ushort4*)&A[(size_t)node * 128 + 4 * f]      = p0.q;
    *(ushort4*)&A[(size_t)node * 128 + 64 + 4 * f] = p1.q;
}

// ---------------------------------------------------------------------------
// 6) update layer 1: h = elu(A@[W1_0;W1_1] + x@root1 + b1). 64-node tile.
// ---------------------------------------------------------------------------
__global__ __launch_bounds__(256) void upd1_kernel(
        const unsigned short* __restrict__ A, const float* __restrict__ x,
        const float* __restrict__ W1, const float* __restrict__ root1,
        const float* __restrict__ b1, float* __restrict__ h) {
    __shared__ float sAT[128][67];
    __shared__ float sXT[64][67];
    const int tid  = threadIdx.x;
    const int w    = tid >> 6;
    const int lane = tid & 63;
    const int base = blockIdx.x * 64;

    {
        const int c = tid & 15;
        const int r = tid >> 4;
        #pragma unroll
        for (int p = 0; p < 4; ++p) {
            const int row  = p * 16 + r;
            const int node = base + row;
            uint4 raw = make_uint4(0u, 0u, 0u, 0u);
            if (node < NN) raw = *(const uint4*)&A[(size_t)node * 128 + c * 8];
            sAT[c * 8 + 0][row] = __uint_as_float(raw.x << 16);
            sAT[c * 8 + 1][row] = __uint_as_float(raw.x & 0xffff0000u);
            sAT[c * 8 + 2][row] = __uint_as_float(raw.y << 16);
            sAT[c * 8 + 3][row] = __uint_as_float(raw.y & 0xffff0000u);
            sAT[c * 8 + 4][row] = __uint_as_float(raw.z << 16);
            sAT[c * 8 + 5][row] = __uint_as_float(raw.z & 0xffff0000u);
            sAT[c * 8 + 6][row] = __uint_as_float(raw.w << 16);
            sAT[c * 8 + 7][row] = __uint_as_float(raw.w & 0xffff0000u);
        }
    }
    {
        const int c4 = tid & 15;
        const int r  = tid >> 4;
        #pragma unroll
        for (int p = 0; p < 4; ++p) {
            const int row  = p * 16 + r;
            const int node = base + row;
            float4 v = make_float4(0.f, 0.f, 0.f, 0.f);
            if (node < NN) v = ((const float4*)x)[(size_t)node * 16 + c4];
            sXT[c4 * 4 + 0][row] = v.x;
            sXT[c4 * 4 + 1][row] = v.y;
            sXT[c4 * 4 + 2][row] = v.z;
            sXT[c4 * 4 + 3][row] = v.w;
        }
    }
    __syncthreads();

    const int cb = __builtin_amdgcn_readfirstlane(w * 16);
    float acc[16];
    #pragma unroll
    for (int c = 0; c < 16; ++c) acc[c] = 0.f;
    #pragma unroll 4
    for (int k = 0; k < 128; ++k) {
        const float a = sAT[k][lane];
        const float* __restrict__ wr = W1 + k * 64 + cb;
        #pragma unroll
        for (int c = 0; c < 16; ++c) acc[c] = fmaf(a, wr[c], acc[c]);
    }
    #pragma unroll 4
    for (int k = 0; k < 64; ++k) {
        const float a = sXT[k][lane];
        const float* __restrict__ wr = root1 + k * 64 + cb;
        #pragma unroll
        for (int c = 0; c < 16; ++c) acc[c] = fmaf(a, wr[c], acc[c]);
    }
    __syncthreads();

    float* bounce = (float*)&sAT[0][0];
    #pragma unroll
    for (int c = 0; c < 16; ++c) {
        const float vv = acc[c] + b1[cb + c];
        bounce[lane * 68 + cb + c] = (vv > 0.f) ? vv : (__expf(vv) - 1.f);
    }
    __syncthreads();
    {
        const int tile_n = (NN - base < 64) ? (NN - base) : 64;
        float4* __restrict__ h4 = (float4*)h;
        for (int fi = tid; fi < tile_n * 16; fi += 256) {
            const int row = fi >> 4, c4 = fi & 15;
            h4[(size_t)base * 16 + fi] = *(const float4*)&bounce[row * 68 + c4 * 4];
        }
    }
}

// ---------------------------------------------------------------------------
// 7) update layer 2 + log_softmax.
// ---------------------------------------------------------------------------
__global__ __launch_bounds__(256) void upd2_kernel(
        const unsigned short* __restrict__ A, const float* __restrict__ hbuf,
        const float* __restrict__ W2, const float* __restrict__ root2,
        const float* __restrict__ b2, float* __restrict__ out) {
    __shared__ float sAT[128][67];
    __shared__ float sXT[64][67];
    __shared__ float sLse[64];
    const int tid  = threadIdx.x;
    const int w    = tid >> 6;
    const int lane = tid & 63;
    const int base = blockIdx.x * 64;

    {
        const int c = tid & 15;
        const int r = tid >> 4;
        #pragma unroll
        for (int p = 0; p < 4; ++p) {
            const int row  = p * 16 + r;
            const int node = base + row;
            uint4 raw = make_uint4(0u, 0u, 0u, 0u);
            if (node < NN) raw = *(const uint4*)&A[(size_t)node * 128 + c * 8];
            sAT[c * 8 + 0][row] = __uint_as_float(raw.x << 16);
            sAT[c * 8 + 1][row] = __uint_as_float(raw.x & 0xffff0000u);
            sAT[c * 8 + 2][row] = __uint_as_float(raw.y << 16);
            sAT[c * 8 + 3][row] = __uint_as_float(raw.y & 0xffff0000u);
            sAT[c * 8 + 4][row] = __uint_as_float(raw.z << 16);
            sAT[c * 8 + 5][row] = __uint_as_float(raw.z & 0xffff0000u);
            sAT[c * 8 + 6][row] = __uint_as_float(raw.w << 16);
            sAT[c * 8 + 7][row] = __uint_as_float(raw.w & 0xffff0000u);
        }
    }
    {
        const int c4 = tid & 15;
        const int r  = tid >> 4;
        #pragma unroll
        for (int p = 0; p < 4; ++p) {
            const int row  = p * 16 + r;
            const int node = base + row;
            float4 v = make_float4(0.f, 0.f, 0.f, 0.f);
            if (node < NN) v = ((const float4*)hbuf)[(size_t)node * 16 + c4];
            sXT[c4 * 4 + 0][row] = v.x;
            sXT[c4 * 4 + 1][row] = v.y;
            sXT[c4 * 4 + 2][row] = v.z;
            sXT[c4 * 4 + 3][row] = v.w;
        }
    }
    __syncthreads();

    const int cb = __builtin_amdgcn_readfirstlane(w * 10);
    float acc[10];
    #pragma unroll
    for (int c = 0; c < 10; ++c) acc[c] = 0.f;
    #pragma unroll 4
    for (int k = 0; k < 128; ++k) {
        const float a = sAT[k][lane];
        const float* __restrict__ wr = W2 + k * 40 + cb;
        #pragma unroll
        for (int c = 0; c < 10; ++c) acc[c] = fmaf(a, wr[c], acc[c]);
    }
    #pragma unroll 4
    for (int k = 0; k < 64; ++k) {
        const float a = sXT[k][lane];
        const float* __restrict__ wr = root2 + k * 40 + cb;
        #pragma unroll
        for (int c = 0; c < 10; ++c) acc[c] = fmaf(a, wr[c], acc[c]);
    }
    __syncthreads();

    float* sOut = (float*)&sAT[0][0];
    #pragma unroll
    for (int c = 0; c < 10; ++c) sOut[lane * 44 + cb + c] = acc[c] + b2[cb + c];
    __syncthreads();
    if (tid < 64) {
        float mx = -3.0e38f;
        #pragma unroll
        for (int c = 0; c < 40; ++c) mx = fmaxf(mx, sOut[tid * 44 + c]);
        float s = 0.f;
        #pragma unroll
        for (int c = 0; c < 40; ++c) s += __expf(sOut[tid * 44 + c] - mx);
        sLse[tid] = mx + __logf(s);
    }
    __syncthreads();
    {
        const int tile_n = (NN - base < 64) ? (NN - base) : 64;
        float4* __restrict__ out4 = (float4*)out;
        for (int fi = tid; fi < tile_n * 10; fi += 256) {
            const int row = fi / 10, c4 = fi - row * 10;
            float4 v = *(const float4*)&sOut[row * 44 + c4 * 4];
            const float l = sLse[row];
            v.x -= l; v.y -= l; v.z -= l; v.w -= l;
            out4[(size_t)base * 10 + fi] = v;
        }
    }
}

// ---------------------------------------------------------------------------
extern "C" void kernel_launch(void* const* d_in, const int* in_sizes, int n_in,
                              void* d_out, int out_size, void* d_ws, size_t ws_size,
                              hipStream_t stream) {
    const float* x     = (const float*)d_in[0];
    const int*   ei    = (const int*)  d_in[1];
    const float* u     = (const float*)d_in[2];
    const float* W1    = (const float*)d_in[3];
    const float* root1 = (const float*)d_in[4];
    const float* b1    = (const float*)d_in[5];
    const float* W2    = (const float*)d_in[6];
    const float* root2 = (const float*)d_in[7];
    const float* b2    = (const float*)d_in[8];
    float*       out   = (float*)d_out;

    const int* src = ei;
    const int* dst = ei + NE;

    // ws: deg | binCnt[512] | binStart[513+pad] | binCur[512] | rowstart |
    //     curpos | brec(u64 E) | rec4(u32 E) | A(bf16 N*128) | h(f32 N*64)
    char* p = (char*)d_ws;
    int* deg      = (int*)p;  p += (size_t)4 * NN;
    int* binCnt   = (int*)p;  p += 4 * 512;
    int* binStart = (int*)p;  p += 4 * 520;          // 513 used, pad to 8B mult
    int* binCur   = (int*)p;  p += 4 * 512;
    int* rowstart = (int*)p;  p += (size_t)4 * NN;
    int* curpos   = (int*)p;  p += (size_t)4 * NN;
    ull* brec     = (ull*)p;  p += (size_t)8 * NE;
    unsigned* rec4 = (unsigned*)p;  p += (size_t)4 * NE;
    unsigned short* A = (unsigned short*)p;  p += (size_t)2 * NN * 128;
    float* h      = (float*)p;

    // zero deg + binCnt (contiguous)
    hipMemsetAsync(deg, 0, (size_t)4 * NN + 4 * 512, stream);

    deg_hist_kernel<<<(NE + 2047) / 2048, 256, 0, stream>>>(dst, deg, binCnt);
    scan_bins_kernel<<<1, 256, 0, stream>>>(binCnt, binStart, binCur);
    scan_nodes_kernel<<<NBINS, 256, 0, stream>>>(deg, binStart, rowstart, curpos);
    p3_bin_scatter_kernel<<<(NE + 2047) / 2048, 256, 0, stream>>>(src, dst, u, binCur, brec);
    p4_final_kernel<<<NBINS, 256, 0, stream>>>(brec, binStart, curpos, rec4);

    const int AB = (NN * 16 + 255) / 256;
    const int NB = (NN + 63) / 64;
    agg_kernel <<<AB, 256, 0, stream>>>(rowstart, deg, rec4, x, A);
    upd1_kernel<<<NB, 256, 0, stream>>>(A, x, W1, root1, b1, h);
    agg_kernel <<<AB, 256, 0, stream>>>(rowstart, deg, rec4, h, A);
    upd2_kernel<<<NB, 256, 0, stream>>>(A, h, W2, root2, b2, out);
}

// Round 8
// 363.490 us; speedup vs baseline: 1.7229x; 1.1086x over previous
//
#include <hip/hip_runtime.h>
#include <math.h>

#define NN 100000
#define NE 1600000
#define NBINS 391          // bin = dst >> 8 ; 100000/256 -> 0..390
// IN = HID = 64, OUT = 40

typedef unsigned long long ull;

__device__ __forceinline__ unsigned short f2bf(float f) {
    unsigned b = __float_as_uint(f);
    return (unsigned short)((b + 0x7fffu + ((b >> 16) & 1u)) >> 16);
}
__device__ __forceinline__ float bf2f(unsigned short s) {
    return __uint_as_float((unsigned)s << 16);
}

// ---------------------------------------------------------------------------
// 0) fp32 -> bf16 table conversion (thread = 4 elems)
// ---------------------------------------------------------------------------
__global__ __launch_bounds__(256) void cvt_kernel(
        const float* __restrict__ in, unsigned short* __restrict__ outb) {
    const int t = blockIdx.x * 256 + threadIdx.x;
    if (t < NN * 16) {
        const float4 v = ((const float4*)in)[t];
        ushort4 q;
        q.x = f2bf(v.x); q.y = f2bf(v.y); q.z = f2bf(v.z); q.w = f2bf(v.w);
        ((ushort4*)outb)[t] = q;
    }
}

// ---------------------------------------------------------------------------
// 1) degree histogram + bin histogram (LDS-staged)
// ---------------------------------------------------------------------------
__global__ __launch_bounds__(256) void deg_hist_kernel(
        const int* __restrict__ dst, int* __restrict__ deg,
        int* __restrict__ binCnt) {
    __shared__ int hist[512];
    const int t = threadIdx.x;
    hist[t] = 0; hist[t + 256] = 0;
    __syncthreads();
    const int b4 = blockIdx.x * 512;   // int4 base
    #pragma unroll
    for (int k = 0; k < 2; ++k) {
        const int i4 = b4 + k * 256 + t;
        if (i4 * 4 < NE) {
            const int4 d4 = ((const int4*)dst)[i4];
            atomicAdd(&deg[d4.x], 1); atomicAdd(&hist[d4.x >> 8], 1);
            atomicAdd(&deg[d4.y], 1); atomicAdd(&hist[d4.y >> 8], 1);
            atomicAdd(&deg[d4.z], 1); atomicAdd(&hist[d4.z >> 8], 1);
            atomicAdd(&deg[d4.w], 1); atomicAdd(&hist[d4.w >> 8], 1);
        }
    }
    __syncthreads();
    if (hist[t])       atomicAdd(&binCnt[t],       hist[t]);
    if (hist[t + 256]) atomicAdd(&binCnt[t + 256], hist[t + 256]);
}

// ---------------------------------------------------------------------------
// 2a) exclusive scan of binCnt[512] -> binStart[513]; binCur = binStart
// ---------------------------------------------------------------------------
__global__ __launch_bounds__(256) void scan_bins_kernel(
        const int* __restrict__ binCnt, int* __restrict__ binStart,
        int* __restrict__ binCur) {
    __shared__ int sa[512], sb[512];
    const int t = threadIdx.x;
    sa[t] = binCnt[t]; sa[t + 256] = binCnt[t + 256];
    __syncthreads();
    int* cur = sa; int* nxt = sb;
    for (int off = 1; off < 512; off <<= 1) {
        for (int j = t; j < 512; j += 256)
            nxt[j] = cur[j] + ((j >= off) ? cur[j - off] : 0);
        __syncthreads();
        int* tmp = cur; cur = nxt; nxt = tmp;
    }
    for (int j = t; j < 512; j += 256) {
        const int ex = (j == 0) ? 0 : cur[j - 1];
        binStart[j] = ex;
        binCur[j]   = ex;
    }
    if (t == 0) binStart[512] = cur[511];
}

// ---------------------------------------------------------------------------
// 2b) per-bin exclusive scan of deg -> rowstart (node-ordered CSR), curpos
// ---------------------------------------------------------------------------
__global__ __launch_bounds__(256) void scan_nodes_kernel(
        const int* __restrict__ deg, const int* __restrict__ binStart,
        int* __restrict__ rowstart, int* __restrict__ curpos) {
    __shared__ int wsum[4];
    const int b = blockIdx.x;
    const int t = threadIdx.x;
    const int n = b * 256 + t;
    const int d = (n < NN) ? deg[n] : 0;
    const int lane = t & 63, w = t >> 6;
    int inc = d;
    for (int off = 1; off < 64; off <<= 1) {
        int v = __shfl_up(inc, off, 64);
        if (lane >= off) inc += v;
    }
    if (lane == 63) wsum[w] = inc;
    __syncthreads();
    int add = 0;
    for (int i = 0; i < 4; ++i) if (i < w) add += wsum[i];
    const int excl = binStart[b] + add + inc - d;
    if (n < NN) { rowstart[n] = excl; curpos[n] = excl; }
}

// ---------------------------------------------------------------------------
// 3) binned scatter with LDS reorder: edges -> brec grouped by bin,
//    coalesced full-line global writes. brec = [uq:15|dst:17]<<32 | src.
// ---------------------------------------------------------------------------
__global__ __launch_bounds__(256) void p3_bin_scatter_kernel(
        const int* __restrict__ src, const int* __restrict__ dst,
        const float* __restrict__ u, int* __restrict__ binCur,
        ull* __restrict__ brec) {
    __shared__ int cnt[512], lstart[512], gbase[512], lcur[512];
    __shared__ int sa[512], sb[512];
    __shared__ ull buf[2048];
    const int t = threadIdx.x;
    cnt[t] = 0; cnt[t + 256] = 0;
    __syncthreads();
    const int base = blockIdx.x * 2048;
    int mysrc[8], mydst[8];
    float myu[8];
    #pragma unroll
    for (int k = 0; k < 8; ++k) {
        const int i = base + k * 256 + t;
        if (i < NE) {
            mydst[k] = dst[i]; mysrc[k] = src[i]; myu[k] = u[i];
            atomicAdd(&cnt[mydst[k] >> 8], 1);
        } else {
            mydst[k] = -1;
        }
    }
    __syncthreads();
    sa[t] = cnt[t]; sa[t + 256] = cnt[t + 256];
    __syncthreads();
    int* cur = sa; int* nxt = sb;
    for (int off = 1; off < 512; off <<= 1) {
        for (int j = t; j < 512; j += 256)
            nxt[j] = cur[j] + ((j >= off) ? cur[j - off] : 0);
        __syncthreads();
        int* tmp = cur; cur = nxt; nxt = tmp;
    }
    for (int j = t; j < 512; j += 256) {
        const int ex = (j == 0) ? 0 : cur[j - 1];
        lstart[j] = ex;
        lcur[j]   = ex;
    }
    __syncthreads();
    for (int j = t; j < 512; j += 256) {
        const int c = cnt[j];
        gbase[j] = c ? atomicAdd(&binCur[j], c) : 0;
    }
    #pragma unroll
    for (int k = 0; k < 8; ++k) {
        if (mydst[k] >= 0) {
            const int b = mydst[k] >> 8;
            const int lp = atomicAdd(&lcur[b], 1);
            int uq = (int)(myu[k] * 32768.0f + 0.5f);
            if (uq > 32767) uq = 32767;
            const unsigned hi = ((unsigned)uq << 17) | (unsigned)mydst[k];
            buf[lp] = ((ull)hi << 32) | (unsigned)mysrc[k];
        }
    }
    __syncthreads();
    const int total = lstart[511] + cnt[511];
    for (int i = t; i < total; i += 256) {
        const ull r = buf[i];
        const int d = (int)((unsigned)(r >> 32) & 0x1FFFFu);
        const int b = d >> 8;
        brec[(size_t)(gbase[b] + (i - lstart[b]))] = r;
    }
}

// ---------------------------------------------------------------------------
// 4) per-bin final scatter: brec -> rec4 in CSR order (bin window L2-local).
//    rec4 = [uq:15]<<17 | src.
// ---------------------------------------------------------------------------
__global__ __launch_bounds__(256) void p4_final_kernel(
        const ull* __restrict__ brec, const int* __restrict__ binStart,
        int* __restrict__ curpos, unsigned* __restrict__ rec4) {
    const int b = blockIdx.x;
    const int s = binStart[b], e = binStart[b + 1];
    for (int i = s + threadIdx.x; i < e; i += 256) {
        const ull r = brec[i];
        const unsigned hi = (unsigned)(r >> 32);
        const int d = hi & 0x1FFFFu;
        const int p = atomicAdd(&curpos[d], 1);
        rec4[p] = (hi & 0xFFFE0000u) | (unsigned)(r & 0x1FFFFu);
    }
}

// ---------------------------------------------------------------------------
// 5) aggregate: CSR gather from bf16 table, NO LDS. 16 threads per node,
//    thread owns 4 features (ushort4 = 8B per edge); 8-deep unrolled loop.
//    Writes A[node][0:64]=(sum-sum_u)/deg, A[node][64:128]=sum_u/deg (bf16).
// ---------------------------------------------------------------------------
__global__ __launch_bounds__(256, 6) void agg_kernel(
        const int* __restrict__ rowstart, const int* __restrict__ deg,
        const unsigned* __restrict__ rec4, const unsigned short* __restrict__ featb,
        unsigned short* __restrict__ A) {
    const int t    = blockIdx.x * 256 + threadIdx.x;
    const int node = t >> 4;
    const int f    = t & 15;
    if (node >= NN) return;
    const int dg = deg[node];
    const int st = rowstart[node];
    const ushort4* __restrict__ f4 = (const ushort4*)featb;
    const float UQS = 1.0f / 32768.0f;

    float4 sum = make_float4(0.f, 0.f, 0.f, 0.f);
    float4 smu = make_float4(0.f, 0.f, 0.f, 0.f);
    int i = 0;
    for (; i + 8 <= dg; i += 8) {
        #pragma unroll
        for (int jj = 0; jj < 8; ++jj) {
            const unsigned r = rec4[(size_t)(st + i + jj)];
            const float u2 = (float)(r >> 17) * UQS;
            const ushort4 q = f4[(size_t)(r & 0x1FFFFu) * 16 + f];
            const float vx = bf2f(q.x), vy = bf2f(q.y), vz = bf2f(q.z), vw = bf2f(q.w);
            sum.x += vx; sum.y += vy; sum.z += vz; sum.w += vw;
            smu.x = fmaf(u2, vx, smu.x);
            smu.y = fmaf(u2, vy, smu.y);
            smu.z = fmaf(u2, vz, smu.z);
            smu.w = fmaf(u2, vw, smu.w);
        }
    }
    #pragma unroll 4
    for (; i < dg; ++i) {
        const unsigned r = rec4[(size_t)(st + i)];
        const float u2 = (float)(r >> 17) * UQS;
        const ushort4 q = f4[(size_t)(r & 0x1FFFFu) * 16 + f];
        const float vx = bf2f(q.x), vy = bf2f(q.y), vz = bf2f(q.z), vw = bf2f(q.w);
        sum.x += vx; sum.y += vy; sum.z += vz; sum.w += vw;
        smu.x = fmaf(u2, vx, smu.x);
        smu.y = fmaf(u2, vy, smu.y);
        smu.z = fmaf(u2, vz, smu.z);
        smu.w = fmaf(u2, vw, smu.w);
    }
    const float inv = 1.0f / fmaxf((float)dg, 1.0f);
    ushort4 p0, p1;
    p0.x = f2bf((sum.x - smu.x) * inv);
    p0.y = f2bf((sum.y - smu.y) * inv);
    p0.z = f2bf((sum.z - smu.z) * inv);
    p0.w = f2bf((sum.w - smu.w) * inv);
    p1.x = f2bf(smu.x * inv);
    p1.y = f2bf(smu.y * inv);
    p1.z = f2bf(smu.z * inv);
    p1.w = f2bf(smu.w * inv);
    *(ushort4*)&A[(size_t)node * 128 + 4 * f]      = p0;
    *(ushort4*)&A[(size_t)node * 128 + 64 + 4 * f] = p1;
}

// ---------------------------------------------------------------------------
// 6) update layer 1: hbf = elu(A@[W1_0;W1_1] + x@root1 + b1)  (bf16 out).
// ---------------------------------------------------------------------------
__global__ __launch_bounds__(256) void upd1_kernel(
        const unsigned short* __restrict__ A, const float* __restrict__ x,
        const float* __restrict__ W1, const float* __restrict__ root1,
        const float* __restrict__ b1, unsigned short* __restrict__ hbf) {
    __shared__ float sAT[128][67];
    __shared__ float sXT[64][67];
    const int tid  = threadIdx.x;
    const int w    = tid >> 6;
    const int lane = tid & 63;
    const int base = blockIdx.x * 64;

    {
        const int c = tid & 15;
        const int r = tid >> 4;
        #pragma unroll
        for (int p = 0; p < 4; ++p) {
            const int row  = p * 16 + r;
            const int node = base + row;
            uint4 raw = make_uint4(0u, 0u, 0u, 0u);
            if (node < NN) raw = *(const uint4*)&A[(size_t)node * 128 + c * 8];
            sAT[c * 8 + 0][row] = __uint_as_float(raw.x << 16);
            sAT[c * 8 + 1][row] = __uint_as_float(raw.x & 0xffff0000u);
            sAT[c * 8 + 2][row] = __uint_as_float(raw.y << 16);
            sAT[c * 8 + 3][row] = __uint_as_float(raw.y & 0xffff0000u);
            sAT[c * 8 + 4][row] = __uint_as_float(raw.z << 16);
            sAT[c * 8 + 5][row] = __uint_as_float(raw.z & 0xffff0000u);
            sAT[c * 8 + 6][row] = __uint_as_float(raw.w << 16);
            sAT[c * 8 + 7][row] = __uint_as_float(raw.w & 0xffff0000u);
        }
    }
    {
        const int c4 = tid & 15;
        const int r  = tid >> 4;
        #pragma unroll
        for (int p = 0; p < 4; ++p) {
            const int row  = p * 16 + r;
            const int node = base + row;
            float4 v = make_float4(0.f, 0.f, 0.f, 0.f);
            if (node < NN) v = ((const float4*)x)[(size_t)node * 16 + c4];
            sXT[c4 * 4 + 0][row] = v.x;
            sXT[c4 * 4 + 1][row] = v.y;
            sXT[c4 * 4 + 2][row] = v.z;
            sXT[c4 * 4 + 3][row] = v.w;
        }
    }
    __syncthreads();

    const int cb = __builtin_amdgcn_readfirstlane(w * 16);
    float acc[16];
    #pragma unroll
    for (int c = 0; c < 16; ++c) acc[c] = 0.f;
    #pragma unroll 4
    for (int k = 0; k < 128; ++k) {
        const float a = sAT[k][lane];
        const float* __restrict__ wr = W1 + k * 64 + cb;
        #pragma unroll
        for (int c = 0; c < 16; ++c) acc[c] = fmaf(a, wr[c], acc[c]);
    }
    #pragma unroll 4
    for (int k = 0; k < 64; ++k) {
        const float a = sXT[k][lane];
        const float* __restrict__ wr = root1 + k * 64 + cb;
        #pragma unroll
        for (int c = 0; c < 16; ++c) acc[c] = fmaf(a, wr[c], acc[c]);
    }
    __syncthreads();

    float* bounce = (float*)&sAT[0][0];
    #pragma unroll
    for (int c = 0; c < 16; ++c) {
        const float vv = acc[c] + b1[cb + c];
        bounce[lane * 68 + cb + c] = (vv > 0.f) ? vv : (__expf(vv) - 1.f);
    }
    __syncthreads();
    {
        const int tile_n = (NN - base < 64) ? (NN - base) : 64;
        for (int fi = tid; fi < tile_n * 16; fi += 256) {
            const int row = fi >> 4, c4 = fi & 15;
            const float4 v = *(const float4*)&bounce[row * 68 + c4 * 4];
            ushort4 q;
            q.x = f2bf(v.x); q.y = f2bf(v.y); q.z = f2bf(v.z); q.w = f2bf(v.w);
            *(ushort4*)&hbf[(size_t)base * 64 + fi * 4] = q;
        }
    }
}

// ---------------------------------------------------------------------------
// 7) update layer 2 + log_softmax (h input in bf16).
// ---------------------------------------------------------------------------
__global__ __launch_bounds__(256) void upd2_kernel(
        const unsigned short* __restrict__ A, const unsigned short* __restrict__ hbf,
        const float* __restrict__ W2, const float* __restrict__ root2,
        const float* __restrict__ b2, float* __restrict__ out) {
    __shared__ float sAT[128][67];
    __shared__ float sXT[64][67];
    __shared__ float sLse[64];
    const int tid  = threadIdx.x;
    const int w    = tid >> 6;
    const int lane = tid & 63;
    const int base = blockIdx.x * 64;

    {
        const int c = tid & 15;
        const int r = tid >> 4;
        #pragma unroll
        for (int p = 0; p < 4; ++p) {
            const int row  = p * 16 + r;
            const int node = base + row;
            uint4 raw = make_uint4(0u, 0u, 0u, 0u);
            if (node < NN) raw = *(const uint4*)&A[(size_t)node * 128 + c * 8];
            sAT[c * 8 + 0][row] = __uint_as_float(raw.x << 16);
            sAT[c * 8 + 1][row] = __uint_as_float(raw.x & 0xffff0000u);
            sAT[c * 8 + 2][row] = __uint_as_float(raw.y << 16);
            sAT[c * 8 + 3][row] = __uint_as_float(raw.y & 0xffff0000u);
            sAT[c * 8 + 4][row] = __uint_as_float(raw.z << 16);
            sAT[c * 8 + 5][row] = __uint_as_float(raw.z & 0xffff0000u);
            sAT[c * 8 + 6][row] = __uint_as_float(raw.w << 16);
            sAT[c * 8 + 7][row] = __uint_as_float(raw.w & 0xffff0000u);
        }
    }
    {
        const int c4 = tid & 15;
        const int r  = tid >> 4;
        #pragma unroll
        for (int p = 0; p < 4; ++p) {
            const int row  = p * 16 + r;
            const int node = base + row;
            ushort4 q = make_ushort4(0, 0, 0, 0);
            if (node < NN) q = *(const ushort4*)&hbf[(size_t)node * 64 + c4 * 4];
            sXT[c4 * 4 + 0][row] = bf2f(q.x);
            sXT[c4 * 4 + 1][row] = bf2f(q.y);
            sXT[c4 * 4 + 2][row] = bf2f(q.z);
            sXT[c4 * 4 + 3][row] = bf2f(q.w);
        }
    }
    __syncthreads();

    const int cb = __builtin_amdgcn_readfirstlane(w * 10);
    float acc[10];
    #pragma unroll
    for (int c = 0; c < 10; ++c) acc[c] = 0.f;
    #pragma unroll 4
    for (int k = 0; k < 128; ++k) {
        const float a = sAT[k][lane];
        const float* __restrict__ wr = W2 + k * 40 + cb;
        #pragma unroll
        for (int c = 0; c < 10; ++c) acc[c] = fmaf(a, wr[c], acc[c]);
    }
    #pragma unroll 4
    for (int k = 0; k < 64; ++k) {
        const float a = sXT[k][lane];
        const float* __restrict__ wr = root2 + k * 40 + cb;
        #pragma unroll
        for (int c = 0; c < 10; ++c) acc[c] = fmaf(a, wr[c], acc[c]);
    }
    __syncthreads();

    float* sOut = (float*)&sAT[0][0];
    #pragma unroll
    for (int c = 0; c < 10; ++c) sOut[lane * 44 + cb + c] = acc[c] + b2[cb + c];
    __syncthreads();
    if (tid < 64) {
        float mx = -3.0e38f;
        #pragma unroll
        for (int c = 0; c < 40; ++c) mx = fmaxf(mx, sOut[tid * 44 + c]);
        float s = 0.f;
        #pragma unroll
        for (int c = 0; c < 40; ++c) s += __expf(sOut[tid * 44 + c] - mx);
        sLse[tid] = mx + __logf(s);
    }
    __syncthreads();
    {
        const int tile_n = (NN - base < 64) ? (NN - base) : 64;
        float4* __restrict__ out4 = (float4*)out;
        for (int fi = tid; fi < tile_n * 10; fi += 256) {
            const int row = fi / 10, c4 = fi - row * 10;
            float4 v = *(const float4*)&sOut[row * 44 + c4 * 4];
            const float l = sLse[row];
            v.x -= l; v.y -= l; v.z -= l; v.w -= l;
            out4[(size_t)base * 10 + fi] = v;
        }
    }
}

// ---------------------------------------------------------------------------
extern "C" void kernel_launch(void* const* d_in, const int* in_sizes, int n_in,
                              void* d_out, int out_size, void* d_ws, size_t ws_size,
                              hipStream_t stream) {
    const float* x     = (const float*)d_in[0];
    const int*   ei    = (const int*)  d_in[1];
    const float* u     = (const float*)d_in[2];
    const float* W1    = (const float*)d_in[3];
    const float* root1 = (const float*)d_in[4];
    const float* b1    = (const float*)d_in[5];
    const float* W2    = (const float*)d_in[6];
    const float* root2 = (const float*)d_in[7];
    const float* b2    = (const float*)d_in[8];
    float*       out   = (float*)d_out;

    const int* src = ei;
    const int* dst = ei + NE;

    // ws: deg | binCnt[512] | binStart[520] | binCur[512] | rowstart | curpos
    //     | brec(u64 E) | rec4(u32 E) | A(bf16 N*128) | xbf(bf16 N*64)
    //     | hbf(bf16 N*64)                               ~= 71.6 MB
    char* p = (char*)d_ws;
    int* deg      = (int*)p;  p += (size_t)4 * NN;
    int* binCnt   = (int*)p;  p += 4 * 512;
    int* binStart = (int*)p;  p += 4 * 520;
    int* binCur   = (int*)p;  p += 4 * 512;
    int* rowstart = (int*)p;  p += (size_t)4 * NN;
    int* curpos   = (int*)p;  p += (size_t)4 * NN;
    ull* brec     = (ull*)p;  p += (size_t)8 * NE;
    unsigned* rec4 = (unsigned*)p;  p += (size_t)4 * NE;
    unsigned short* A   = (unsigned short*)p;  p += (size_t)2 * NN * 128;
    unsigned short* xbf = (unsigned short*)p;  p += (size_t)2 * NN * 64;
    unsigned short* hbf = (unsigned short*)p;

    hipMemsetAsync(deg, 0, (size_t)4 * NN + 4 * 512, stream);

    cvt_kernel<<<(NN * 16 + 255) / 256, 256, 0, stream>>>(x, xbf);
    deg_hist_kernel<<<(NE + 2047) / 2048, 256, 0, stream>>>(dst, deg, binCnt);
    scan_bins_kernel<<<1, 256, 0, stream>>>(binCnt, binStart, binCur);
    scan_nodes_kernel<<<NBINS, 256, 0, stream>>>(deg, binStart, rowstart, curpos);
    p3_bin_scatter_kernel<<<(NE + 2047) / 2048, 256, 0, stream>>>(src, dst, u, binCur, brec);
    p4_final_kernel<<<NBINS, 256, 0, stream>>>(brec, binStart, curpos, rec4);

    const int AB = (NN * 16 + 255) / 256;
    const int NB = (NN + 63) / 64;
    agg_kernel <<<AB, 256, 0, stream>>>(rowstart, deg, rec4, xbf, A);
    upd1_kernel<<<NB, 256, 0, stream>>>(A, x, W1, root1, b1, hbf);
    agg_kernel <<<AB, 256, 0, stream>>>(rowstart, deg, rec4, hbf, A);
    upd2_kernel<<<NB, 256, 0, stream>>>(A, hbf, W2, root2, b2, out);
}

// Round 9
// 277.704 us; speedup vs baseline: 2.2551x; 1.3089x over previous
//
#include <hip/hip_runtime.h>
#include <math.h>

#define NN 100000
#define NE 1600000
#define NBINS 391          // bin = dst >> 8 ; 100000/256 -> 0..390
// IN = HID = 64, OUT = 40

typedef unsigned long long ull;

__device__ __forceinline__ unsigned short f2bf(float f) {
    unsigned b = __float_as_uint(f);
    return (unsigned short)((b + 0x7fffu + ((b >> 16) & 1u)) >> 16);
}
__device__ __forceinline__ float bf2f(unsigned short s) {
    return __uint_as_float((unsigned)s << 16);
}

// ---------------------------------------------------------------------------
// 0) fp32 -> bf16 table conversion (thread = 4 elems)
// ---------------------------------------------------------------------------
__global__ __launch_bounds__(256) void cvt_kernel(
        const float* __restrict__ in, unsigned short* __restrict__ outb) {
    const int t = blockIdx.x * 256 + threadIdx.x;
    if (t < NN * 16) {
        const float4 v = ((const float4*)in)[t];
        ushort4 q;
        q.x = f2bf(v.x); q.y = f2bf(v.y); q.z = f2bf(v.z); q.w = f2bf(v.w);
        ((ushort4*)outb)[t] = q;
    }
}

// ---------------------------------------------------------------------------
// 1) bin histogram ONLY (no per-node atomics). 8192 edges per wg.
// ---------------------------------------------------------------------------
__global__ __launch_bounds__(256) void hist_kernel(
        const int* __restrict__ dst, int* __restrict__ binCnt) {
    __shared__ int hist[512];
    const int t = threadIdx.x;
    hist[t] = 0; hist[t + 256] = 0;
    __syncthreads();
    const int b4 = blockIdx.x * 2048;   // int4 base
    #pragma unroll
    for (int k = 0; k < 8; ++k) {
        const int i4 = b4 + k * 256 + t;
        if (i4 * 4 < NE) {
            const int4 d4 = ((const int4*)dst)[i4];
            atomicAdd(&hist[d4.x >> 8], 1);
            atomicAdd(&hist[d4.y >> 8], 1);
            atomicAdd(&hist[d4.z >> 8], 1);
            atomicAdd(&hist[d4.w >> 8], 1);
        }
    }
    __syncthreads();
    if (hist[t])       atomicAdd(&binCnt[t],       hist[t]);
    if (hist[t + 256]) atomicAdd(&binCnt[t + 256], hist[t + 256]);
}

// ---------------------------------------------------------------------------
// 2) exclusive scan of binCnt[512] -> binStart[513]; binCur = binStart
// ---------------------------------------------------------------------------
__global__ __launch_bounds__(256) void scan_bins_kernel(
        const int* __restrict__ binCnt, int* __restrict__ binStart,
        int* __restrict__ binCur) {
    __shared__ int sa[512], sb[512];
    const int t = threadIdx.x;
    sa[t] = binCnt[t]; sa[t + 256] = binCnt[t + 256];
    __syncthreads();
    int* cur = sa; int* nxt = sb;
    for (int off = 1; off < 512; off <<= 1) {
        for (int j = t; j < 512; j += 256)
            nxt[j] = cur[j] + ((j >= off) ? cur[j - off] : 0);
        __syncthreads();
        int* tmp = cur; cur = nxt; nxt = tmp;
    }
    for (int j = t; j < 512; j += 256) {
        const int ex = (j == 0) ? 0 : cur[j - 1];
        binStart[j] = ex;
        binCur[j]   = ex;
    }
    if (t == 0) binStart[512] = cur[511];
}

// ---------------------------------------------------------------------------
// 3) binned scatter with LDS reorder: edges -> brec grouped by bin,
//    coalesced full-line global writes. brec = [uq:15|dst:17]<<32 | src.
// ---------------------------------------------------------------------------
__global__ __launch_bounds__(256) void p3_bin_scatter_kernel(
        const int* __restrict__ src, const int* __restrict__ dst,
        const float* __restrict__ u, int* __restrict__ binCur,
        ull* __restrict__ brec) {
    __shared__ int cnt[512], lstart[512], gbase[512], lcur[512];
    __shared__ int sa[512], sb[512];
    __shared__ ull buf[2048];
    const int t = threadIdx.x;
    cnt[t] = 0; cnt[t + 256] = 0;
    __syncthreads();
    const int base = blockIdx.x * 2048;
    int mysrc[8], mydst[8];
    float myu[8];
    #pragma unroll
    for (int k = 0; k < 8; ++k) {
        const int i = base + k * 256 + t;
        if (i < NE) {
            mydst[k] = dst[i]; mysrc[k] = src[i]; myu[k] = u[i];
            atomicAdd(&cnt[mydst[k] >> 8], 1);
        } else {
            mydst[k] = -1;
        }
    }
    __syncthreads();
    sa[t] = cnt[t]; sa[t + 256] = cnt[t + 256];
    __syncthreads();
    int* cur = sa; int* nxt = sb;
    for (int off = 1; off < 512; off <<= 1) {
        for (int j = t; j < 512; j += 256)
            nxt[j] = cur[j] + ((j >= off) ? cur[j - off] : 0);
        __syncthreads();
        int* tmp = cur; cur = nxt; nxt = tmp;
    }
    for (int j = t; j < 512; j += 256) {
        const int ex = (j == 0) ? 0 : cur[j - 1];
        lstart[j] = ex;
        lcur[j]   = ex;
    }
    __syncthreads();
    for (int j = t; j < 512; j += 256) {
        const int c = cnt[j];
        gbase[j] = c ? atomicAdd(&binCur[j], c) : 0;
    }
    #pragma unroll
    for (int k = 0; k < 8; ++k) {
        if (mydst[k] >= 0) {
            const int b = mydst[k] >> 8;
            const int lp = atomicAdd(&lcur[b], 1);
            int uq = (int)(myu[k] * 32768.0f + 0.5f);
            if (uq > 32767) uq = 32767;
            const unsigned hi = ((unsigned)uq << 17) | (unsigned)mydst[k];
            buf[lp] = ((ull)hi << 32) | (unsigned)mysrc[k];
        }
    }
    __syncthreads();
    const int total = lstart[511] + cnt[511];
    for (int i = t; i < total; i += 256) {
        const ull r = buf[i];
        const int d = (int)((unsigned)(r >> 32) & 0x1FFFFu);
        const int b = d >> 8;
        brec[(size_t)(gbase[b] + (i - lstart[b]))] = r;
    }
}

// ---------------------------------------------------------------------------
// 4) per-bin finalize: derive deg + rowstart from the bin's records (LDS
//    histogram + scan, coalesced non-atomic writes), then scatter to CSR
//    order with LDS cursors. rec4 = [uq:15]<<17 | src. Bin window L2-local.
// ---------------------------------------------------------------------------
__global__ __launch_bounds__(256) void p4_final_kernel(
        const ull* __restrict__ brec, const int* __restrict__ binStart,
        int* __restrict__ deg, int* __restrict__ rowstart,
        unsigned* __restrict__ rec4) {
    __shared__ int cnt[256], lpos[256], wsum[4];
    const int b = blockIdx.x;
    const int s = binStart[b], e = binStart[b + 1];
    const int t = threadIdx.x;
    cnt[t] = 0;
    __syncthreads();
    for (int i = s + t; i < e; i += 256)
        atomicAdd(&cnt[(unsigned)(brec[i] >> 32) & 0xFFu], 1);
    __syncthreads();
    // exclusive scan of cnt[256]
    const int lane = t & 63, w = t >> 6;
    const int v = cnt[t];
    int inc = v;
    for (int off = 1; off < 64; off <<= 1) {
        int tv = __shfl_up(inc, off, 64);
        if (lane >= off) inc += tv;
    }
    if (lane == 63) wsum[w] = inc;
    __syncthreads();
    int add = 0;
    #pragma unroll
    for (int i = 0; i < 4; ++i) if (i < w) add += wsum[i];
    const int excl = add + inc - v;
    const int node = b * 256 + t;
    if (node < NN) {
        deg[node]      = v;
        rowstart[node] = s + excl;
    }
    lpos[t] = s + excl;
    __syncthreads();
    for (int i = s + t; i < e; i += 256) {
        const ull r = brec[i];
        const unsigned hi = (unsigned)(r >> 32);
        const int p = atomicAdd(&lpos[hi & 0xFFu], 1);
        rec4[p] = (hi & 0xFFFE0000u) | (unsigned)(r & 0x1FFFFu);
    }
}

// ---------------------------------------------------------------------------
// 5) aggregate: CSR gather from bf16 table, NO LDS. 16 threads per node,
//    thread owns 4 features (ushort4 = 8B per edge); 8-deep unrolled loop.
//    Writes A[node][0:64]=(sum-sum_u)/deg, A[node][64:128]=sum_u/deg (bf16).
// ---------------------------------------------------------------------------
__global__ __launch_bounds__(256, 6) void agg_kernel(
        const int* __restrict__ rowstart, const int* __restrict__ deg,
        const unsigned* __restrict__ rec4, const unsigned short* __restrict__ featb,
        unsigned short* __restrict__ A) {
    const int t    = blockIdx.x * 256 + threadIdx.x;
    const int node = t >> 4;
    const int f    = t & 15;
    if (node >= NN) return;
    const int dg = deg[node];
    const int st = rowstart[node];
    const ushort4* __restrict__ f4 = (const ushort4*)featb;
    const float UQS = 1.0f / 32768.0f;

    float4 sum = make_float4(0.f, 0.f, 0.f, 0.f);
    float4 smu = make_float4(0.f, 0.f, 0.f, 0.f);
    int i = 0;
    for (; i + 8 <= dg; i += 8) {
        #pragma unroll
        for (int jj = 0; jj < 8; ++jj) {
            const unsigned r = rec4[(size_t)(st + i + jj)];
            const float u2 = (float)(r >> 17) * UQS;
            const ushort4 q = f4[(size_t)(r & 0x1FFFFu) * 16 + f];
            const float vx = bf2f(q.x), vy = bf2f(q.y), vz = bf2f(q.z), vw = bf2f(q.w);
            sum.x += vx; sum.y += vy; sum.z += vz; sum.w += vw;
            smu.x = fmaf(u2, vx, smu.x);
            smu.y = fmaf(u2, vy, smu.y);
            smu.z = fmaf(u2, vz, smu.z);
            smu.w = fmaf(u2, vw, smu.w);
        }
    }
    #pragma unroll 4
    for (; i < dg; ++i) {
        const unsigned r = rec4[(size_t)(st + i)];
        const float u2 = (float)(r >> 17) * UQS;
        const ushort4 q = f4[(size_t)(r & 0x1FFFFu) * 16 + f];
        const float vx = bf2f(q.x), vy = bf2f(q.y), vz = bf2f(q.z), vw = bf2f(q.w);
        sum.x += vx; sum.y += vy; sum.z += vz; sum.w += vw;
        smu.x = fmaf(u2, vx, smu.x);
        smu.y = fmaf(u2, vy, smu.y);
        smu.z = fmaf(u2, vz, smu.z);
        smu.w = fmaf(u2, vw, smu.w);
    }
    const float inv = 1.0f / fmaxf((float)dg, 1.0f);
    ushort4 p0, p1;
    p0.x = f2bf((sum.x - smu.x) * inv);
    p0.y = f2bf((sum.y - smu.y) * inv);
    p0.z = f2bf((sum.z - smu.z) * inv);
    p0.w = f2bf((sum.w - smu.w) * inv);
    p1.x = f2bf(smu.x * inv);
    p1.y = f2bf(smu.y * inv);
    p1.z = f2bf(smu.z * inv);
    p1.w = f2bf(smu.w * inv);
    *(ushort4*)&A[(size_t)node * 128 + 4 * f]      = p0;
    *(ushort4*)&A[(size_t)node * 128 + 64 + 4 * f] = p1;
}

// ---------------------------------------------------------------------------
// 6) update layer 1: hbf = elu(A@[W1_0;W1_1] + x@root1 + b1)  (bf16 out).
// ---------------------------------------------------------------------------
__global__ __launch_bounds__(256) void upd1_kernel(
        const unsigned short* __restrict__ A, const float* __restrict__ x,
        const float* __restrict__ W1, const float* __restrict__ root1,
        const float* __restrict__ b1, unsigned short* __restrict__ hbf) {
    __shared__ float sAT[128][67];
    __shared__ float sXT[64][67];
    const int tid  = threadIdx.x;
    const int w    = tid >> 6;
    const int lane = tid & 63;
    const int base = blockIdx.x * 64;

    {
        const int c = tid & 15;
        const int r = tid >> 4;
        #pragma unroll
        for (int p = 0; p < 4; ++p) {
            const int row  = p * 16 + r;
            const int node = base + row;
            uint4 raw = make_uint4(0u, 0u, 0u, 0u);
            if (node < NN) raw = *(const uint4*)&A[(size_t)node * 128 + c * 8];
            sAT[c * 8 + 0][row] = __uint_as_float(raw.x << 16);
            sAT[c * 8 + 1][row] = __uint_as_float(raw.x & 0xffff0000u);
            sAT[c * 8 + 2][row] = __uint_as_float(raw.y << 16);
            sAT[c * 8 + 3][row] = __uint_as_float(raw.y & 0xffff0000u);
            sAT[c * 8 + 4][row] = __uint_as_float(raw.z << 16);
            sAT[c * 8 + 5][row] = __uint_as_float(raw.z & 0xffff0000u);
            sAT[c * 8 + 6][row] = __uint_as_float(raw.w << 16);
            sAT[c * 8 + 7][row] = __uint_as_float(raw.w & 0xffff0000u);
        }
    }
    {
        const int c4 = tid & 15;
        const int r  = tid >> 4;
        #pragma unroll
        for (int p = 0; p < 4; ++p) {
            const int row  = p * 16 + r;
            const int node = base + row;
            float4 v = make_float4(0.f, 0.f, 0.f, 0.f);
            if (node < NN) v = ((const float4*)x)[(size_t)node * 16 + c4];
            sXT[c4 * 4 + 0][row] = v.x;
            sXT[c4 * 4 + 1][row] = v.y;
            sXT[c4 * 4 + 2][row] = v.z;
            sXT[c4 * 4 + 3][row] = v.w;
        }
    }
    __syncthreads();

    const int cb = __builtin_amdgcn_readfirstlane(w * 16);
    float acc[16];
    #pragma unroll
    for (int c = 0; c < 16; ++c) acc[c] = 0.f;
    #pragma unroll 4
    for (int k = 0; k < 128; ++k) {
        const float a = sAT[k][lane];
        const float* __restrict__ wr = W1 + k * 64 + cb;
        #pragma unroll
        for (int c = 0; c < 16; ++c) acc[c] = fmaf(a, wr[c], acc[c]);
    }
    #pragma unroll 4
    for (int k = 0; k < 64; ++k) {
        const float a = sXT[k][lane];
        const float* __restrict__ wr = root1 + k * 64 + cb;
        #pragma unroll
        for (int c = 0; c < 16; ++c) acc[c] = fmaf(a, wr[c], acc[c]);
    }
    __syncthreads();

    float* bounce = (float*)&sAT[0][0];
    #pragma unroll
    for (int c = 0; c < 16; ++c) {
        const float vv = acc[c] + b1[cb + c];
        bounce[lane * 68 + cb + c] = (vv > 0.f) ? vv : (__expf(vv) - 1.f);
    }
    __syncthreads();
    {
        const int tile_n = (NN - base < 64) ? (NN - base) : 64;
        for (int fi = tid; fi < tile_n * 16; fi += 256) {
            const int row = fi >> 4, c4 = fi & 15;
            const float4 v = *(const float4*)&bounce[row * 68 + c4 * 4];
            ushort4 q;
            q.x = f2bf(v.x); q.y = f2bf(v.y); q.z = f2bf(v.z); q.w = f2bf(v.w);
            *(ushort4*)&hbf[(size_t)base * 64 + fi * 4] = q;
        }
    }
}

// ---------------------------------------------------------------------------
// 7) update layer 2 + log_softmax (h input in bf16).
// ---------------------------------------------------------------------------
__global__ __launch_bounds__(256) void upd2_kernel(
        const unsigned short* __restrict__ A, const unsigned short* __restrict__ hbf,
        const float* __restrict__ W2, const float* __restrict__ root2,
        const float* __restrict__ b2, float* __restrict__ out) {
    __shared__ float sAT[128][67];
    __shared__ float sXT[64][67];
    __shared__ float sLse[64];
    const int tid  = threadIdx.x;
    const int w    = tid >> 6;
    const int lane = tid & 63;
    const int base = blockIdx.x * 64;

    {
        const int c = tid & 15;
        const int r = tid >> 4;
        #pragma unroll
        for (int p = 0; p < 4; ++p) {
            const int row  = p * 16 + r;
            const int node = base + row;
            uint4 raw = make_uint4(0u, 0u, 0u, 0u);
            if (node < NN) raw = *(const uint4*)&A[(size_t)node * 128 + c * 8];
            sAT[c * 8 + 0][row] = __uint_as_float(raw.x << 16);
            sAT[c * 8 + 1][row] = __uint_as_float(raw.x & 0xffff0000u);
            sAT[c * 8 + 2][row] = __uint_as_float(raw.y << 16);
            sAT[c * 8 + 3][row] = __uint_as_float(raw.y & 0xffff0000u);
            sAT[c * 8 + 4][row] = __uint_as_float(raw.z << 16);
            sAT[c * 8 + 5][row] = __uint_as_float(raw.z & 0xffff0000u);
            sAT[c * 8 + 6][row] = __uint_as_float(raw.w << 16);
            sAT[c * 8 + 7][row] = __uint_as_float(raw.w & 0xffff0000u);
        }
    }
    {
        const int c4 = tid & 15;
        const int r  = tid >> 4;
        #pragma unroll
        for (int p = 0; p < 4; ++p) {
            const int row  = p * 16 + r;
            const int node = base + row;
            ushort4 q = make_ushort4(0, 0, 0, 0);
            if (node < NN) q = *(const ushort4*)&hbf[(size_t)node * 64 + c4 * 4];
            sXT[c4 * 4 + 0][row] = bf2f(q.x);
            sXT[c4 * 4 + 1][row] = bf2f(q.y);
            sXT[c4 * 4 + 2][row] = bf2f(q.z);
            sXT[c4 * 4 + 3][row] = bf2f(q.w);
        }
    }
    __syncthreads();

    const int cb = __builtin_amdgcn_readfirstlane(w * 10);
    float acc[10];
    #pragma unroll
    for (int c = 0; c < 10; ++c) acc[c] = 0.f;
    #pragma unroll 4
    for (int k = 0; k < 128; ++k) {
        const float a = sAT[k][lane];
        const float* __restrict__ wr = W2 + k * 40 + cb;
        #pragma unroll
        for (int c = 0; c < 10; ++c) acc[c] = fmaf(a, wr[c], acc[c]);
    }
    #pragma unroll 4
    for (int k = 0; k < 64; ++k) {
        const float a = sXT[k][lane];
        const float* __restrict__ wr = root2 + k * 40 + cb;
        #pragma unroll
        for (int c = 0; c < 10; ++c) acc[c] = fmaf(a, wr[c], acc[c]);
    }
    __syncthreads();

    float* sOut = (float*)&sAT[0][0];
    #pragma unroll
    for (int c = 0; c < 10; ++c) sOut[lane * 44 + cb + c] = acc[c] + b2[cb + c];
    __syncthreads();
    if (tid < 64) {
        float mx = -3.0e38f;
        #pragma unroll
        for (int c = 0; c < 40; ++c) mx = fmaxf(mx, sOut[tid * 44 + c]);
        float s = 0.f;
        #pragma unroll
        for (int c = 0; c < 40; ++c) s += __expf(sOut[tid * 44 + c] - mx);
        sLse[tid] = mx + __logf(s);
    }
    __syncthreads();
    {
        const int tile_n = (NN - base < 64) ? (NN - base) : 64;
        float4* __restrict__ out4 = (float4*)out;
        for (int fi = tid; fi < tile_n * 10; fi += 256) {
            const int row = fi / 10, c4 = fi - row * 10;
            float4 v = *(const float4*)&sOut[row * 44 + c4 * 4];
            const float l = sLse[row];
            v.x -= l; v.y -= l; v.z -= l; v.w -= l;
            out4[(size_t)base * 10 + fi] = v;
        }
    }
}

// ---------------------------------------------------------------------------
extern "C" void kernel_launch(void* const* d_in, const int* in_sizes, int n_in,
                              void* d_out, int out_size, void* d_ws, size_t ws_size,
                              hipStream_t stream) {
    const float* x     = (const float*)d_in[0];
    const int*   ei    = (const int*)  d_in[1];
    const float* u     = (const float*)d_in[2];
    const float* W1    = (const float*)d_in[3];
    const float* root1 = (const float*)d_in[4];
    const float* b1    = (const float*)d_in[5];
    const float* W2    = (const float*)d_in[6];
    const float* root2 = (const float*)d_in[7];
    const float* b2    = (const float*)d_in[8];
    float*       out   = (float*)d_out;

    const int* src = ei;
    const int* dst = ei + NE;

    // ws: binCnt[512] | binStart[520] | binCur[512] | deg | rowstart |
    //     brec(u64 E) | rec4(u32 E) | A(bf16 N*128) | xbf | hbf   ~= 71 MB
    char* p = (char*)d_ws;
    int* binCnt   = (int*)p;  p += 4 * 512;
    int* binStart = (int*)p;  p += 4 * 520;
    int* binCur   = (int*)p;  p += 4 * 512;
    int* deg      = (int*)p;  p += (size_t)4 * NN;
    int* rowstart = (int*)p;  p += (size_t)4 * NN;
    ull* brec     = (ull*)p;  p += (size_t)8 * NE;
    unsigned* rec4 = (unsigned*)p;  p += (size_t)4 * NE;
    unsigned short* A   = (unsigned short*)p;  p += (size_t)2 * NN * 128;
    unsigned short* xbf = (unsigned short*)p;  p += (size_t)2 * NN * 64;
    unsigned short* hbf = (unsigned short*)p;

    hipMemsetAsync(binCnt, 0, 4 * 512, stream);

    cvt_kernel<<<(NN * 16 + 255) / 256, 256, 0, stream>>>(x, xbf);
    hist_kernel<<<(NE + 8191) / 8192, 256, 0, stream>>>(dst, binCnt);
    scan_bins_kernel<<<1, 256, 0, stream>>>(binCnt, binStart, binCur);
    p3_bin_scatter_kernel<<<(NE + 2047) / 2048, 256, 0, stream>>>(src, dst, u, binCur, brec);
    p4_final_kernel<<<NBINS, 256, 0, stream>>>(brec, binStart, deg, rowstart, rec4);

    const int AB = (NN * 16 + 255) / 256;
    const int NB = (NN + 63) / 64;
    agg_kernel <<<AB, 256, 0, stream>>>(rowstart, deg, rec4, xbf, A);
    upd1_kernel<<<NB, 256, 0, stream>>>(A, x, W1, root1, b1, hbf);
    agg_kernel <<<AB, 256, 0, stream>>>(rowstart, deg, rec4, hbf, A);
    upd2_kernel<<<NB, 256, 0, stream>>>(A, hbf, W2, root2, b2, out);
}

// Round 10
// 219.307 us; speedup vs baseline: 2.8556x; 1.2663x over previous
//
#include <hip/hip_runtime.h>
#include <math.h>

#define NN 100000
#define NE 1600000
#define NBINS 391          // bin = dst >> 8 ; 100000/256 -> 0..390
// IN = HID = 64, OUT = 40

typedef unsigned long long ull;
typedef float f32x4 __attribute__((ext_vector_type(4)));
typedef short s16x8 __attribute__((ext_vector_type(8)));

__device__ __forceinline__ unsigned short f2bf(float f) {
    unsigned b = __float_as_uint(f);
    return (unsigned short)((b + 0x7fffu + ((b >> 16) & 1u)) >> 16);
}
__device__ __forceinline__ float bf2f(unsigned short s) {
    return __uint_as_float((unsigned)s << 16);
}

// ---------------------------------------------------------------------------
// 0) fp32 -> bf16 table conversion (thread = 4 elems)
// ---------------------------------------------------------------------------
__global__ __launch_bounds__(256) void cvt_kernel(
        const float* __restrict__ in, unsigned short* __restrict__ outb) {
    const int t = blockIdx.x * 256 + threadIdx.x;
    if (t < NN * 16) {
        const float4 v = ((const float4*)in)[t];
        ushort4 q;
        q.x = f2bf(v.x); q.y = f2bf(v.y); q.z = f2bf(v.z); q.w = f2bf(v.w);
        ((ushort4*)outb)[t] = q;
    }
}

// ---------------------------------------------------------------------------
// 0b) pack W1|root1 into MFMA B-fragment order: Bp[kb][ct][lane][8]
//     (kb: 6 k-steps of 32 over K=192=[W1 128 | root1 64]; ct: 4 col tiles)
// ---------------------------------------------------------------------------
__global__ __launch_bounds__(256) void pack1_kernel(
        const float* __restrict__ W1, const float* __restrict__ root1,
        unsigned short* __restrict__ Bp) {
    const int gid = blockIdx.x * 256 + threadIdx.x;
    if (gid >= 6 * 4 * 64) return;
    const int kb = gid >> 8;           // 4*64 = 256 frags per kb
    const int ct = (gid >> 6) & 3;
    const int l  = gid & 63;
    const int n  = ct * 16 + (l & 15);
    const int k0 = kb * 32 + (l >> 4) * 8;
    #pragma unroll
    for (int j = 0; j < 8; ++j) {
        const int k = k0 + j;
        const float v = (k < 128) ? W1[k * 64 + n] : root1[(k - 128) * 64 + n];
        Bp[gid * 8 + j] = f2bf(v);
    }
}

// ---------------------------------------------------------------------------
// 0c) pack W2|root2 (N padded 40->48): Bp[kb][ct:3][lane][8]
// ---------------------------------------------------------------------------
__global__ __launch_bounds__(256) void pack2_kernel(
        const float* __restrict__ W2, const float* __restrict__ root2,
        unsigned short* __restrict__ Bp) {
    const int gid = blockIdx.x * 256 + threadIdx.x;
    if (gid >= 6 * 3 * 64) return;
    const int kb = gid / 192;
    const int r  = gid - kb * 192;
    const int ct = r >> 6;
    const int l  = r & 63;
    const int n  = ct * 16 + (l & 15);
    const int k0 = kb * 32 + (l >> 4) * 8;
    #pragma unroll
    for (int j = 0; j < 8; ++j) {
        const int k = k0 + j;
        float v = 0.f;
        if (n < 40) v = (k < 128) ? W2[k * 40 + n] : root2[(k - 128) * 40 + n];
        Bp[gid * 8 + j] = f2bf(v);
    }
}

// ---------------------------------------------------------------------------
// 1) bin histogram ONLY (no per-node atomics). 8192 edges per wg.
// ---------------------------------------------------------------------------
__global__ __launch_bounds__(256) void hist_kernel(
        const int* __restrict__ dst, int* __restrict__ binCnt) {
    __shared__ int hist[512];
    const int t = threadIdx.x;
    hist[t] = 0; hist[t + 256] = 0;
    __syncthreads();
    const int b4 = blockIdx.x * 2048;   // int4 base
    #pragma unroll
    for (int k = 0; k < 8; ++k) {
        const int i4 = b4 + k * 256 + t;
        if (i4 * 4 < NE) {
            const int4 d4 = ((const int4*)dst)[i4];
            atomicAdd(&hist[d4.x >> 8], 1);
            atomicAdd(&hist[d4.y >> 8], 1);
            atomicAdd(&hist[d4.z >> 8], 1);
            atomicAdd(&hist[d4.w >> 8], 1);
        }
    }
    __syncthreads();
    if (hist[t])       atomicAdd(&binCnt[t],       hist[t]);
    if (hist[t + 256]) atomicAdd(&binCnt[t + 256], hist[t + 256]);
}

// ---------------------------------------------------------------------------
// 2) exclusive scan of binCnt[512] -> binStart[513]; binCur = binStart
// ---------------------------------------------------------------------------
__global__ __launch_bounds__(256) void scan_bins_kernel(
        const int* __restrict__ binCnt, int* __restrict__ binStart,
        int* __restrict__ binCur) {
    __shared__ int sa[512], sb[512];
    const int t = threadIdx.x;
    sa[t] = binCnt[t]; sa[t + 256] = binCnt[t + 256];
    __syncthreads();
    int* cur = sa; int* nxt = sb;
    for (int off = 1; off < 512; off <<= 1) {
        for (int j = t; j < 512; j += 256)
            nxt[j] = cur[j] + ((j >= off) ? cur[j - off] : 0);
        __syncthreads();
        int* tmp = cur; cur = nxt; nxt = tmp;
    }
    for (int j = t; j < 512; j += 256) {
        const int ex = (j == 0) ? 0 : cur[j - 1];
        binStart[j] = ex;
        binCur[j]   = ex;
    }
    if (t == 0) binStart[512] = cur[511];
}

// ---------------------------------------------------------------------------
// 3) binned scatter with LDS reorder: edges -> brec grouped by bin,
//    coalesced full-line global writes. brec = [uq:15|dst:17]<<32 | src.
// ---------------------------------------------------------------------------
__global__ __launch_bounds__(256) void p3_bin_scatter_kernel(
        const int* __restrict__ src, const int* __restrict__ dst,
        const float* __restrict__ u, int* __restrict__ binCur,
        ull* __restrict__ brec) {
    __shared__ int cnt[512], lstart[512], gbase[512], lcur[512];
    __shared__ int sa[512], sb[512];
    __shared__ ull buf[2048];
    const int t = threadIdx.x;
    cnt[t] = 0; cnt[t + 256] = 0;
    __syncthreads();
    const int base = blockIdx.x * 2048;
    int mysrc[8], mydst[8];
    float myu[8];
    #pragma unroll
    for (int k = 0; k < 8; ++k) {
        const int i = base + k * 256 + t;
        if (i < NE) {
            mydst[k] = dst[i]; mysrc[k] = src[i]; myu[k] = u[i];
            atomicAdd(&cnt[mydst[k] >> 8], 1);
        } else {
            mydst[k] = -1;
        }
    }
    __syncthreads();
    sa[t] = cnt[t]; sa[t + 256] = cnt[t + 256];
    __syncthreads();
    int* cur = sa; int* nxt = sb;
    for (int off = 1; off < 512; off <<= 1) {
        for (int j = t; j < 512; j += 256)
            nxt[j] = cur[j] + ((j >= off) ? cur[j - off] : 0);
        __syncthreads();
        int* tmp = cur; cur = nxt; nxt = tmp;
    }
    for (int j = t; j < 512; j += 256) {
        const int ex = (j == 0) ? 0 : cur[j - 1];
        lstart[j] = ex;
        lcur[j]   = ex;
    }
    __syncthreads();
    for (int j = t; j < 512; j += 256) {
        const int c = cnt[j];
        gbase[j] = c ? atomicAdd(&binCur[j], c) : 0;
    }
    #pragma unroll
    for (int k = 0; k < 8; ++k) {
        if (mydst[k] >= 0) {
            const int b = mydst[k] >> 8;
            const int lp = atomicAdd(&lcur[b], 1);
            int uq = (int)(myu[k] * 32768.0f + 0.5f);
            if (uq > 32767) uq = 32767;
            const unsigned hi = ((unsigned)uq << 17) | (unsigned)mydst[k];
            buf[lp] = ((ull)hi << 32) | (unsigned)mysrc[k];
        }
    }
    __syncthreads();
    const int total = lstart[511] + cnt[511];
    for (int i = t; i < total; i += 256) {
        const ull r = buf[i];
        const int d = (int)((unsigned)(r >> 32) & 0x1FFFFu);
        const int b = d >> 8;
        brec[(size_t)(gbase[b] + (i - lstart[b]))] = r;
    }
}

// ---------------------------------------------------------------------------
// 4) per-bin finalize: derive deg + rowstart from the bin's records (LDS
//    histogram + scan), then scatter to CSR order with LDS cursors.
//    rec4 = [uq:15]<<17 | src. Bin window L2-local.
// ---------------------------------------------------------------------------
__global__ __launch_bounds__(256) void p4_final_kernel(
        const ull* __restrict__ brec, const int* __restrict__ binStart,
        int* __restrict__ deg, int* __restrict__ rowstart,
        unsigned* __restrict__ rec4) {
    __shared__ int cnt[256], lpos[256], wsum[4];
    const int b = blockIdx.x;
    const int s = binStart[b], e = binStart[b + 1];
    const int t = threadIdx.x;
    cnt[t] = 0;
    __syncthreads();
    for (int i = s + t; i < e; i += 256)
        atomicAdd(&cnt[(unsigned)(brec[i] >> 32) & 0xFFu], 1);
    __syncthreads();
    const int lane = t & 63, w = t >> 6;
    const int v = cnt[t];
    int inc = v;
    for (int off = 1; off < 64; off <<= 1) {
        int tv = __shfl_up(inc, off, 64);
        if (lane >= off) inc += tv;
    }
    if (lane == 63) wsum[w] = inc;
    __syncthreads();
    int add = 0;
    #pragma unroll
    for (int i = 0; i < 4; ++i) if (i < w) add += wsum[i];
    const int excl = add + inc - v;
    const int node = b * 256 + t;
    if (node < NN) {
        deg[node]      = v;
        rowstart[node] = s + excl;
    }
    lpos[t] = s + excl;
    __syncthreads();
    for (int i = s + t; i < e; i += 256) {
        const ull r = brec[i];
        const unsigned hi = (unsigned)(r >> 32);
        const int p = atomicAdd(&lpos[hi & 0xFFu], 1);
        rec4[p] = (hi & 0xFFFE0000u) | (unsigned)(r & 0x1FFFFu);
    }
}

// ---------------------------------------------------------------------------
// 5) aggregate: CSR gather from bf16 table, NO LDS. 16 threads per node.
//    Writes A[node][0:64]=(sum-sum_u)/deg, A[node][64:128]=sum_u/deg (bf16).
// ---------------------------------------------------------------------------
__global__ __launch_bounds__(256, 6) void agg_kernel(
        const int* __restrict__ rowstart, const int* __restrict__ deg,
        const unsigned* __restrict__ rec4, const unsigned short* __restrict__ featb,
        unsigned short* __restrict__ A) {
    const int t    = blockIdx.x * 256 + threadIdx.x;
    const int node = t >> 4;
    const int f    = t & 15;
    if (node >= NN) return;
    const int dg = deg[node];
    const int st = rowstart[node];
    const ushort4* __restrict__ f4 = (const ushort4*)featb;
    const float UQS = 1.0f / 32768.0f;

    float4 sum = make_float4(0.f, 0.f, 0.f, 0.f);
    float4 smu = make_float4(0.f, 0.f, 0.f, 0.f);
    int i = 0;
    for (; i + 8 <= dg; i += 8) {
        #pragma unroll
        for (int jj = 0; jj < 8; ++jj) {
            const unsigned r = rec4[(size_t)(st + i + jj)];
            const float u2 = (float)(r >> 17) * UQS;
            const ushort4 q = f4[(size_t)(r & 0x1FFFFu) * 16 + f];
            const float vx = bf2f(q.x), vy = bf2f(q.y), vz = bf2f(q.z), vw = bf2f(q.w);
            sum.x += vx; sum.y += vy; sum.z += vz; sum.w += vw;
            smu.x = fmaf(u2, vx, smu.x);
            smu.y = fmaf(u2, vy, smu.y);
            smu.z = fmaf(u2, vz, smu.z);
            smu.w = fmaf(u2, vw, smu.w);
        }
    }
    #pragma unroll 4
    for (; i < dg; ++i) {
        const unsigned r = rec4[(size_t)(st + i)];
        const float u2 = (float)(r >> 17) * UQS;
        const ushort4 q = f4[(size_t)(r & 0x1FFFFu) * 16 + f];
        const float vx = bf2f(q.x), vy = bf2f(q.y), vz = bf2f(q.z), vw = bf2f(q.w);
        sum.x += vx; sum.y += vy; sum.z += vz; sum.w += vw;
        smu.x = fmaf(u2, vx, smu.x);
        smu.y = fmaf(u2, vy, smu.y);
        smu.z = fmaf(u2, vz, smu.z);
        smu.w = fmaf(u2, vw, smu.w);
    }
    const float inv = 1.0f / fmaxf((float)dg, 1.0f);
    ushort4 p0, p1;
    p0.x = f2bf((sum.x - smu.x) * inv);
    p0.y = f2bf((sum.y - smu.y) * inv);
    p0.z = f2bf((sum.z - smu.z) * inv);
    p0.w = f2bf((sum.w - smu.w) * inv);
    p1.x = f2bf(smu.x * inv);
    p1.y = f2bf(smu.y * inv);
    p1.z = f2bf(smu.z * inv);
    p1.w = f2bf(smu.w * inv);
    *(ushort4*)&A[(size_t)node * 128 + 4 * f]      = p0;
    *(ushort4*)&A[(size_t)node * 128 + 64 + 4 * f] = p1;
}

// ---------------------------------------------------------------------------
// 6) update layer 1 (MFMA): hbf = elu([A|x] @ Bp1 + b1), 64-node block,
//    wave w = rows 16w..16w+15, K=192 (6 k-steps), N=64 (4 col-tiles).
// ---------------------------------------------------------------------------
__global__ __launch_bounds__(256) void upd1_kernel(
        const unsigned short* __restrict__ A, const unsigned short* __restrict__ xbf,
        const s16x8* __restrict__ Bp, const float* __restrict__ b1,
        unsigned short* __restrict__ hbf) {
    const int tid = threadIdx.x;
    const int w = tid >> 6, l = tid & 63;
    const int kg = l >> 4;
    const int base = blockIdx.x * 64;
    int arow = base + w * 16 + (l & 15);
    if (arow >= NN) arow = NN - 1;
    const s16x8* __restrict__ Ar = (const s16x8*)(A   + (size_t)arow * 128);
    const s16x8* __restrict__ Xr = (const s16x8*)(xbf + (size_t)arow * 64);

    s16x8 af[6];
    #pragma unroll
    for (int kb = 0; kb < 4; ++kb) af[kb] = Ar[kb * 4 + kg];
    af[4] = Xr[kg];
    af[5] = Xr[4 + kg];

    f32x4 acc[4];
    #pragma unroll
    for (int ct = 0; ct < 4; ++ct) acc[ct] = (f32x4){0.f, 0.f, 0.f, 0.f};
    #pragma unroll
    for (int kb = 0; kb < 6; ++kb) {
        #pragma unroll
        for (int ct = 0; ct < 4; ++ct) {
            acc[ct] = __builtin_amdgcn_mfma_f32_16x16x32_bf16(
                af[kb], Bp[(kb * 4 + ct) * 64 + l], acc[ct], 0, 0, 0);
        }
    }

    const int orow0 = base + w * 16 + kg * 4;
    #pragma unroll
    for (int ct = 0; ct < 4; ++ct) {
        const float bv = b1[ct * 16 + (l & 15)];
        #pragma unroll
        for (int j = 0; j < 4; ++j) {
            float v = acc[ct][j] + bv;
            v = (v > 0.f) ? v : (__expf(v) - 1.f);
            const int row = orow0 + j;
            if (row < NN) hbf[(size_t)row * 64 + ct * 16 + (l & 15)] = f2bf(v);
        }
    }
}

// ---------------------------------------------------------------------------
// 7) update layer 2 + log_softmax (MFMA): out = lsm([A|h] @ Bp2 + b2),
//    N padded to 48 (3 col-tiles), cols 40..47 masked in softmax.
// ---------------------------------------------------------------------------
__global__ __launch_bounds__(256) void upd2_kernel(
        const unsigned short* __restrict__ A, const unsigned short* __restrict__ hbf,
        const s16x8* __restrict__ Bp, const float* __restrict__ b2,
        float* __restrict__ out) {
    const int tid = threadIdx.x;
    const int w = tid >> 6, l = tid & 63;
    const int kg = l >> 4;
    const int base = blockIdx.x * 64;
    int arow = base + w * 16 + (l & 15);
    if (arow >= NN) arow = NN - 1;
    const s16x8* __restrict__ Ar = (const s16x8*)(A   + (size_t)arow * 128);
    const s16x8* __restrict__ Xr = (const s16x8*)(hbf + (size_t)arow * 64);

    s16x8 af[6];
    #pragma unroll
    for (int kb = 0; kb < 4; ++kb) af[kb] = Ar[kb * 4 + kg];
    af[4] = Xr[kg];
    af[5] = Xr[4 + kg];

    f32x4 acc[3];
    #pragma unroll
    for (int ct = 0; ct < 3; ++ct) acc[ct] = (f32x4){0.f, 0.f, 0.f, 0.f};
    #pragma unroll
    for (int kb = 0; kb < 6; ++kb) {
        #pragma unroll
        for (int ct = 0; ct < 3; ++ct) {
            acc[ct] = __builtin_amdgcn_mfma_f32_16x16x32_bf16(
                af[kb], Bp[(kb * 3 + ct) * 64 + l], acc[ct], 0, 0, 0);
        }
    }

    const int col = l & 15;
    const float b0 = b2[col], b1v = b2[16 + col];
    const float b2v = (col < 8) ? b2[32 + col] : 0.f;
    #pragma unroll
    for (int j = 0; j < 4; ++j) {
        const float v0 = acc[0][j] + b0;
        const float v1 = acc[1][j] + b1v;
        const float v2 = (col < 8) ? (acc[2][j] + b2v) : -3.0e38f;
        float m = fmaxf(fmaxf(v0, v1), v2);
        #pragma unroll
        for (int off = 1; off < 16; off <<= 1) m = fmaxf(m, __shfl_xor(m, off, 64));
        float s = __expf(v0 - m) + __expf(v1 - m) + ((col < 8) ? __expf(v2 - m) : 0.f);
        #pragma unroll
        for (int off = 1; off < 16; off <<= 1) s += __shfl_xor(s, off, 64);
        const float lse = m + __logf(s);
        const int row = base + w * 16 + kg * 4 + j;
        if (row < NN) {
            float* __restrict__ orow = out + (size_t)row * 40;
            orow[col]      = v0 - lse;
            orow[16 + col] = v1 - lse;
            if (col < 8) orow[32 + col] = v2 - lse;
        }
    }
}

// ---------------------------------------------------------------------------
extern "C" void kernel_launch(void* const* d_in, const int* in_sizes, int n_in,
                              void* d_out, int out_size, void* d_ws, size_t ws_size,
                              hipStream_t stream) {
    const float* x     = (const float*)d_in[0];
    const int*   ei    = (const int*)  d_in[1];
    const float* u     = (const float*)d_in[2];
    const float* W1    = (const float*)d_in[3];
    const float* root1 = (const float*)d_in[4];
    const float* b1    = (const float*)d_in[5];
    const float* W2    = (const float*)d_in[6];
    const float* root2 = (const float*)d_in[7];
    const float* b2    = (const float*)d_in[8];
    float*       out   = (float*)d_out;

    const int* src = ei;
    const int* dst = ei + NE;

    // ws: binCnt[512] | binStart[520] | binCur[512] | deg | rowstart |
    //     brec(u64 E) | rec4(u32 E) | A(bf16 N*128) | xbf | hbf | Bp1 | Bp2
    char* p = (char*)d_ws;
    int* binCnt   = (int*)p;  p += 4 * 512;
    int* binStart = (int*)p;  p += 4 * 520;
    int* binCur   = (int*)p;  p += 4 * 512;
    int* deg      = (int*)p;  p += (size_t)4 * NN;
    int* rowstart = (int*)p;  p += (size_t)4 * NN;
    ull* brec     = (ull*)p;  p += (size_t)8 * NE;
    unsigned* rec4 = (unsigned*)p;  p += (size_t)4 * NE;
    unsigned short* A   = (unsigned short*)p;  p += (size_t)2 * NN * 128;
    unsigned short* xbf = (unsigned short*)p;  p += (size_t)2 * NN * 64;
    unsigned short* hbf = (unsigned short*)p;  p += (size_t)2 * NN * 64;
    unsigned short* Bp1 = (unsigned short*)p;  p += (size_t)2 * 6 * 4 * 64 * 8;
    unsigned short* Bp2 = (unsigned short*)p;  p += (size_t)2 * 6 * 3 * 64 * 8;

    hipMemsetAsync(binCnt, 0, 4 * 512, stream);

    cvt_kernel<<<(NN * 16 + 255) / 256, 256, 0, stream>>>(x, xbf);
    pack1_kernel<<<6, 256, 0, stream>>>(W1, root1, Bp1);
    pack2_kernel<<<5, 256, 0, stream>>>(W2, root2, Bp2);
    hist_kernel<<<(NE + 8191) / 8192, 256, 0, stream>>>(dst, binCnt);
    scan_bins_kernel<<<1, 256, 0, stream>>>(binCnt, binStart, binCur);
    p3_bin_scatter_kernel<<<(NE + 2047) / 2048, 256, 0, stream>>>(src, dst, u, binCur, brec);
    p4_final_kernel<<<NBINS, 256, 0, stream>>>(brec, binStart, deg, rowstart, rec4);

    const int AB = (NN * 16 + 255) / 256;
    const int NB = (NN + 63) / 64;
    agg_kernel <<<AB, 256, 0, stream>>>(rowstart, deg, rec4, xbf, A);
    upd1_kernel<<<NB, 256, 0, stream>>>(A, xbf, (const s16x8*)Bp1, b1, hbf);
    agg_kernel <<<AB, 256, 0, stream>>>(rowstart, deg, rec4, hbf, A);
    upd2_kernel<<<NB, 256, 0, stream>>>(A, hbf, (const s16x8*)Bp2, b2, out);
}